// Round 2
// baseline (1568.126 us; speedup 1.0000x reference)
//
#include <hip/hip_runtime.h>
#include <hip/hip_bf16.h>

typedef __hip_bfloat16 bf16;

#define Bn 8
#define Cc 128
#define Hh 128
#define Wl 128
#define HW (Hh*Wl)
#define NT (Bn*HW)   // 131072 tokens

__device__ __forceinline__ float b2f(bf16 v){ return __bfloat162float(v); }
__device__ __forceinline__ bf16  f2b(float v){ return __float2bfloat16(v); }

// ---------------- depthwise 3x3 conv + bias + residual, write channel-last fp32 ----------------
__global__ __launch_bounds__(128) void conv_kernel(const float* __restrict__ x,
                                                   const float* __restrict__ cw,
                                                   const float* __restrict__ cb,
                                                   float* __restrict__ xt){
  int blk = blockIdx.x;             // ((b*C + c)*H + h)
  int h = blk % Hh; int bc = blk / Hh;
  int c = bc % Cc;  int b = bc / Cc;
  int w = threadIdx.x;
  const float* xp = x + ((size_t)(b*Cc + c))*HW;
  float wgt[9];
#pragma unroll
  for(int i=0;i<9;i++) wgt[i] = cw[c*9+i];
  float acc = cb[c];
#pragma unroll
  for(int dh=-1; dh<=1; dh++){
    int hh = h+dh;
    if(hh<0 || hh>=Hh) continue;
#pragma unroll
    for(int dw=-1; dw<=1; dw++){
      int ww = w+dw;
      if(ww<0 || ww>=Wl) continue;
      acc += wgt[(dh+1)*3 + (dw+1)] * xp[hh*Wl + ww];
    }
  }
  float val = xp[h*Wl + w] + acc;
  xt[((size_t)(b*HW + h*Wl + w))*Cc + c] = val;
}

// ---------------- LayerNorm over C=128, one wave per token ----------------
__global__ __launch_bounds__(256) void ln_kernel(const float* __restrict__ xt,
                                                 const float* __restrict__ wv,
                                                 const float* __restrict__ bv,
                                                 bf16* __restrict__ xn){
  int tok  = blockIdx.x*4 + (threadIdx.x>>6);
  int lane = threadIdx.x & 63;
  const float* row = xt + (size_t)tok*Cc;
  float v0 = row[lane], v1 = row[lane+64];
  float s = v0+v1;
#pragma unroll
  for(int off=32; off; off>>=1) s += __shfl_down(s, off, 64);
  s = __shfl(s, 0, 64);
  float m = s * (1.0f/128.0f);
  float d0 = v0-m, d1 = v1-m;
  float vs = d0*d0 + d1*d1;
#pragma unroll
  for(int off=32; off; off>>=1) vs += __shfl_down(vs, off, 64);
  vs = __shfl(vs, 0, 64);
  float rstd = rsqrtf(vs*(1.0f/128.0f) + 1e-5f);
  bf16* orow = xn + (size_t)tok*Cc;
  orow[lane]    = f2b(d0*rstd*wv[lane]    + bv[lane]);
  orow[lane+64] = f2b(d1*rstd*wv[lane+64] + bv[lane+64]);
}

// ---------------- generic tiled GEMM, bf16 A / fp32 W, fp32 accum ----------------
// EPI: 0 = plain bf16 store (qkv)
//      1 = +bias, exact GELU, bf16 store (fc1)
//      2 = +bias, xt += ls*val (proj residual, fp32 rmw)
//      3 = +bias, out = bf16(xt + ls*val) (fc2 residual, token-major store)
template<int EPI>
__global__ __launch_bounds__(256) void gemm_kernel(const bf16* __restrict__ A,
                                                   const float* __restrict__ Bw,
                                                   const float* __restrict__ bias,
                                                   bf16* __restrict__ outb,
                                                   float* __restrict__ xt,
                                                   const float* __restrict__ ls,
                                                   int M, int N, int K){
  __shared__ float As[16][65];
  __shared__ float Bs[16][65];
  int m0 = blockIdx.y*64, n0 = blockIdx.x*64;
  int tid = threadIdx.x;
  int tx = tid & 15, ty = tid >> 4;
  float acc[4][4] = {};
  for(int k0=0; k0<K; k0+=16){
#pragma unroll
    for(int i=0;i<4;i++){
      int idx = tid + i*256;
      int row = idx >> 4, kk = idx & 15;
      As[kk][row] = b2f(A[(size_t)(m0+row)*K + k0+kk]);
    }
#pragma unroll
    for(int i=0;i<4;i++){
      int idx = tid + i*256;
      int kk = idx >> 6, col = idx & 63;
      Bs[kk][col] = Bw[(size_t)(k0+kk)*N + n0+col];
    }
    __syncthreads();
#pragma unroll
    for(int kk=0;kk<16;kk++){
      float ra[4], rb[4];
#pragma unroll
      for(int i=0;i<4;i++) ra[i]=As[kk][ty*4+i];
#pragma unroll
      for(int j=0;j<4;j++) rb[j]=Bs[kk][tx*4+j];
#pragma unroll
      for(int i=0;i<4;i++)
#pragma unroll
        for(int j=0;j<4;j++) acc[i][j] += ra[i]*rb[j];
    }
    __syncthreads();
  }
#pragma unroll
  for(int i=0;i<4;i++){
    int row = m0 + ty*4 + i;
#pragma unroll
    for(int j=0;j<4;j++){
      int col = n0 + tx*4 + j;
      float v = acc[i][j];
      if(EPI==0){
        outb[(size_t)row*N + col] = f2b(v);
      } else if(EPI==1){
        v += bias[col];
        v = 0.5f*v*(1.0f + erff(v*0.70710678118f));
        outb[(size_t)row*N + col] = f2b(v);
      } else if(EPI==2){
        v += bias[col];
        xt[(size_t)row*128 + col] += ls[col]*v;
      } else {
        v += bias[col];
        float r = xt[(size_t)row*128 + col] + ls[col]*v;
        outb[(size_t)row*128 + col] = f2b(r);
      }
    }
  }
}

// ---------------- local window attention: seq=64, hd=16, heads 0..3 ----------------
__global__ __launch_bounds__(64) void attn_local(const bf16* __restrict__ qkv,
                                                 bf16* __restrict__ a){
  int idx = blockIdx.x;         // ((b*16+bh)*16+bw)*4 + head
  int head = idx & 3; idx >>= 2;
  int bw = idx & 15; idx >>= 4;
  int bh = idx & 15; int b = idx >> 4;
  int p = threadIdx.x;          // si*8+sj
  int si = p >> 3, sj = p & 7;
  size_t tok = (size_t)b*HW + (size_t)(bh*8+si)*Wl + (bw*8+sj);
  const bf16* base = qkv + tok*384 + head*16;
  __shared__ float Ks[64][16], Vs[64][16];
  float q[16];
#pragma unroll
  for(int d=0;d<16;d++){
    q[d]     = b2f(base[d]);
    Ks[p][d] = b2f(base[128+d]);
    Vs[p][d] = b2f(base[256+d]);
  }
  __syncthreads();
  float m=-1e30f, l=0.f, acc[16]={};
  for(int j=0;j<64;j++){
    float s=0.f;
#pragma unroll
    for(int d=0;d<16;d++) s += q[d]*Ks[j][d];
    s *= 0.25f;
    float mn = fmaxf(m,s);
    float corr = __expf(m-mn);
    float pr   = __expf(s-mn);
    l = l*corr + pr;
#pragma unroll
    for(int d=0;d<16;d++) acc[d] = acc[d]*corr + pr*Vs[j][d];
    m = mn;
  }
  float inv = 1.0f/l;
  bf16* ap = a + tok*Cc + head*16;
#pragma unroll
  for(int d=0;d<16;d++) ap[d] = f2b(acc[d]*inv);
}

// ---------------- grid attention: seq=256 (grid cells), hd=16, heads 4..7 ----------------
__global__ __launch_bounds__(256) void attn_grid(const bf16* __restrict__ qkv,
                                                 bf16* __restrict__ a){
  int idx = blockIdx.x;         // ((b*8+si)*8+sj)*4 + hl
  int hl = idx & 3; idx >>= 2;
  int sj = idx & 7; idx >>= 3;
  int si = idx & 7; int b = idx >> 3;
  int g = threadIdx.x;          // bh*16+bw
  int bh = g >> 4, bw = g & 15;
  size_t tok = (size_t)b*HW + (size_t)(bh*8+si)*Wl + (bw*8+sj);
  const bf16* base = qkv + tok*384 + (4+hl)*16;
  __shared__ float Ks[256][16], Vs[256][16];
  float q[16];
#pragma unroll
  for(int d=0;d<16;d++){
    q[d]     = b2f(base[d]);
    Ks[g][d] = b2f(base[128+d]);
    Vs[g][d] = b2f(base[256+d]);
  }
  __syncthreads();
  float m=-1e30f, l=0.f, acc[16]={};
  for(int j=0;j<256;j++){
    float s=0.f;
#pragma unroll
    for(int d=0;d<16;d++) s += q[d]*Ks[j][d];
    s *= 0.25f;
    float mn = fmaxf(m,s);
    float corr = __expf(m-mn);
    float pr   = __expf(s-mn);
    l = l*corr + pr;
#pragma unroll
    for(int d=0;d<16;d++) acc[d] = acc[d]*corr + pr*Vs[j][d];
    m = mn;
  }
  float inv = 1.0f/l;
  bf16* ap = a + tok*Cc + 64 + hl*16;
#pragma unroll
  for(int d=0;d<16;d++) ap[d] = f2b(acc[d]*inv);
}

// ---------------- (B, HW, C) -> (B, C, HW) transpose, bf16 -> fp32 out ----------------
__global__ __launch_bounds__(256) void transpose_kernel(const bf16* __restrict__ xf,
                                                        float* __restrict__ out){
  __shared__ bf16 tile[32][33];
  int t0 = blockIdx.x*32, c0 = blockIdx.y*32, b = blockIdx.z;
  int x = threadIdx.x, y = threadIdx.y;   // 32, 8
  const bf16* src = xf + (size_t)b*HW*Cc;
  float* dst = out + (size_t)b*Cc*HW;
#pragma unroll
  for(int i=0;i<4;i++)
    tile[y*4+i][x] = src[(size_t)(t0 + y*4+i)*Cc + c0 + x];
  __syncthreads();
#pragma unroll
  for(int i=0;i<4;i++)
    dst[(size_t)(c0 + y*4+i)*HW + t0 + x] = b2f(tile[x][y*4+i]);
}

extern "C" void kernel_launch(void* const* d_in, const int* in_sizes, int n_in,
                              void* d_out, int out_size, void* d_ws, size_t ws_size,
                              hipStream_t stream) {
  const float* x       = (const float*)d_in[0];
  const float* conv_w  = (const float*)d_in[1];
  const float* conv_b  = (const float*)d_in[2];
  const float* norm1_w = (const float*)d_in[3];
  const float* norm1_b = (const float*)d_in[4];
  const float* wqkv    = (const float*)d_in[5];
  const float* proj_w  = (const float*)d_in[6];
  const float* proj_b  = (const float*)d_in[7];
  const float* norm2_w = (const float*)d_in[8];
  const float* norm2_b = (const float*)d_in[9];
  const float* fc1_w   = (const float*)d_in[10];
  const float* fc1_b   = (const float*)d_in[11];
  const float* fc2_w   = (const float*)d_in[12];
  const float* fc2_b   = (const float*)d_in[13];
  const float* ls1     = (const float*)d_in[14];
  const float* ls2     = (const float*)d_in[15];
  float* out = (float*)d_out;

  char* ws = (char*)d_ws;
  float* xt = (float*)ws;                                   // N*128*4 = 64 MiB
  bf16*  sh = (bf16*)(ws + (size_t)NT*Cc*4);                // N*128*2: xn -> a -> xn2 -> xt_final
  bf16*  qh = (bf16*)(ws + (size_t)NT*Cc*4 + (size_t)NT*Cc*2); // N*512*2: qkv then h1

  // 1. depthwise conv + bias + residual -> xt (fp32, token-major)
  conv_kernel<<<Bn*Cc*Hh, 128, 0, stream>>>(x, conv_w, conv_b, xt);
  // 2. LN1 -> sh (xn)
  ln_kernel<<<NT/4, 256, 0, stream>>>(xt, norm1_w, norm1_b, sh);
  // 3. qkv = xn @ wqkv  (N x 384)
  gemm_kernel<0><<<dim3(384/64, NT/64), 256, 0, stream>>>(sh, wqkv, nullptr, qh, nullptr, nullptr, NT, 384, 128);
  // 4a. local window attention -> sh channels [0,64)
  attn_local<<<Bn*16*16*4, 64, 0, stream>>>(qh, sh);
  // 4b. grid attention -> sh channels [64,128)
  attn_grid<<<Bn*8*8*4, 256, 0, stream>>>(qh, sh);
  // 5. proj + ls1 residual into xt
  gemm_kernel<2><<<dim3(128/64, NT/64), 256, 0, stream>>>(sh, proj_w, proj_b, nullptr, xt, ls1, NT, 128, 128);
  // 6. LN2 -> sh (xn2)
  ln_kernel<<<NT/4, 256, 0, stream>>>(xt, norm2_w, norm2_b, sh);
  // 7. fc1 + GELU -> qh (h1, N x 512)
  gemm_kernel<1><<<dim3(512/64, NT/64), 256, 0, stream>>>(sh, fc1_w, fc1_b, qh, nullptr, nullptr, NT, 512, 128);
  // 8. fc2 + ls2 residual -> sh (xt_final, bf16 token-major)
  gemm_kernel<3><<<dim3(128/64, NT/64), 256, 0, stream>>>(qh, fc2_w, fc2_b, sh, xt, ls2, NT, 128, 512);
  // 9. transpose to (B, C, HW)
  transpose_kernel<<<dim3(HW/32, Cc/32, Bn), dim3(32,8), 0, stream>>>(sh, out);
}

// Round 3
// 830.678 us; speedup vs baseline: 1.8878x; 1.8878x over previous
//
#include <hip/hip_runtime.h>
#include <hip/hip_bf16.h>

typedef __hip_bfloat16 bf16;
typedef __attribute__((ext_vector_type(8))) short short8;
typedef __attribute__((ext_vector_type(4))) float floatx4;

#define Bn 8
#define Cc 128
#define Hh 128
#define Wl 128
#define HW (Hh*Wl)
#define NT (Bn*HW)   // 131072 tokens

__device__ __forceinline__ float b2f(bf16 v){ return __bfloat162float(v); }
__device__ __forceinline__ bf16  f2b(float v){ return __float2bfloat16(v); }

// ---------------- weight cast+transpose: W[K][N] fp32 -> Wt[N][K] bf16 ----------------
__global__ __launch_bounds__(256) void transpose_w(const float* __restrict__ src,
                                                   bf16* __restrict__ dst, int K, int N){
  int idx = blockIdx.x*256 + threadIdx.x;
  if(idx >= K*N) return;
  int n = idx % N, k = idx / N;
  dst[(size_t)n*K + k] = f2b(src[idx]);
}

// ---------------- depthwise 3x3 conv + bias + residual, write channel-last fp32 ----------------
__global__ __launch_bounds__(128) void conv_kernel(const float* __restrict__ x,
                                                   const float* __restrict__ cw,
                                                   const float* __restrict__ cb,
                                                   float* __restrict__ xt){
  int blk = blockIdx.x;             // ((b*C + c)*H + h)
  int h = blk % Hh; int bc = blk / Hh;
  int c = bc % Cc;  int b = bc / Cc;
  int w = threadIdx.x;
  const float* xp = x + ((size_t)(b*Cc + c))*HW;
  float wgt[9];
#pragma unroll
  for(int i=0;i<9;i++) wgt[i] = cw[c*9+i];
  float acc = cb[c];
#pragma unroll
  for(int dh=-1; dh<=1; dh++){
    int hh = h+dh;
    if(hh<0 || hh>=Hh) continue;
#pragma unroll
    for(int dw=-1; dw<=1; dw++){
      int ww = w+dw;
      if(ww<0 || ww>=Wl) continue;
      acc += wgt[(dh+1)*3 + (dw+1)] * xp[hh*Wl + ww];
    }
  }
  float val = xp[h*Wl + w] + acc;
  xt[((size_t)(b*HW + h*Wl + w))*Cc + c] = val;
}

// ---------------- LayerNorm over C=128, one wave per token ----------------
__global__ __launch_bounds__(256) void ln_kernel(const float* __restrict__ xt,
                                                 const float* __restrict__ wv,
                                                 const float* __restrict__ bv,
                                                 bf16* __restrict__ xn){
  int tok  = blockIdx.x*4 + (threadIdx.x>>6);
  int lane = threadIdx.x & 63;
  const float* row = xt + (size_t)tok*Cc;
  float v0 = row[lane], v1 = row[lane+64];
  float s = v0+v1;
#pragma unroll
  for(int off=32; off; off>>=1) s += __shfl_down(s, off, 64);
  s = __shfl(s, 0, 64);
  float m = s * (1.0f/128.0f);
  float d0 = v0-m, d1 = v1-m;
  float vs = d0*d0 + d1*d1;
#pragma unroll
  for(int off=32; off; off>>=1) vs += __shfl_down(vs, off, 64);
  vs = __shfl(vs, 0, 64);
  float rstd = rsqrtf(vs*(1.0f/128.0f) + 1e-5f);
  bf16* orow = xn + (size_t)tok*Cc;
  orow[lane]    = f2b(d0*rstd*wv[lane]    + bv[lane]);
  orow[lane+64] = f2b(d1*rstd*wv[lane+64] + bv[lane+64]);
}

// ---------------- MFMA bf16 GEMM: C[M][N] = A[M][K] @ W[K][N], Wt[N][K] given ----------------
// Tile: BM=128, BN=64, BK=32. 4 waves, each 64(m) x 32(n).
// LDS fragment-order layout [tile][quad][row16][8]: frag read = base + lane*16B (conflict-free).
// EPI: 0 = bf16 store (qkv); 1 = +bias,GELU,bf16 (fc1); 2 = +bias, xt += ls*v (proj);
//      3 = +bias, out = bf16(xt + ls*v) (fc2)
template<int EPI>
__global__ __launch_bounds__(256) void mfma_gemm(const bf16* __restrict__ A,
                                                 const bf16* __restrict__ Wt,
                                                 const float* __restrict__ bias,
                                                 bf16* __restrict__ outb,
                                                 float* __restrict__ xt,
                                                 const float* __restrict__ ls,
                                                 int N, int K){
  __shared__ short As[128*32];   // [mtile8][quad4][m16][8]
  __shared__ short Bs[64*32];    // [ntile4][quad4][n16][8]
  const int m0 = blockIdx.y*128, n0 = blockIdx.x*64;
  const int tid = threadIdx.x;
  const int lane = tid & 63;
  const int w = tid >> 6;
  const int wm = (w&1)*64;     // wave m-offset (m-tiles (w&1)*4 ..+4)
  const int wn = (w>>1)*32;    // wave n-offset (n-tiles (w>>1)*2 ..+2)

  floatx4 acc[4][2];
#pragma unroll
  for(int i=0;i<4;i++)
#pragma unroll
    for(int j=0;j<2;j++) acc[i][j] = (floatx4){0.f,0.f,0.f,0.f};

  for(int k0=0; k0<K; k0+=32){
    // stage A: 512 chunks of 16B
#pragma unroll
    for(int p=0;p<2;p++){
      int ch = tid + p*256;
      int r = ch & 127, c = ch >> 7;
      short8 v = *(const short8*)(A + (size_t)(m0+r)*K + k0 + c*8);
      int lidx = ((r>>4)*4 + c)*16 + (r&15);
      *(short8*)&As[lidx*8] = v;
    }
    // stage B: 256 chunks
    {
      int n = tid & 63, c = tid >> 6;
      short8 v = *(const short8*)(Wt + (size_t)(n0+n)*K + k0 + c*8);
      int lidx = ((n>>4)*4 + c)*16 + (n&15);
      *(short8*)&Bs[lidx*8] = v;
    }
    __syncthreads();
    short8 af[4], bfr[2];
#pragma unroll
    for(int mt=0;mt<4;mt++) af[mt] = *(short8*)&As[(((w&1)*4+mt)*64 + lane)*8];
#pragma unroll
    for(int nt=0;nt<2;nt++) bfr[nt] = *(short8*)&Bs[(((w>>1)*2+nt)*64 + lane)*8];
#pragma unroll
    for(int mt=0;mt<4;mt++)
#pragma unroll
      for(int nt=0;nt<2;nt++)
        acc[mt][nt] = __builtin_amdgcn_mfma_f32_16x16x32_bf16(af[mt], bfr[nt], acc[mt][nt], 0, 0, 0);
    __syncthreads();
  }

  // epilogue: C/D layout col=lane&15, row=(lane>>4)*4+reg
#pragma unroll
  for(int mt=0;mt<4;mt++){
#pragma unroll
    for(int nt=0;nt<2;nt++){
#pragma unroll
      for(int r=0;r<4;r++){
        int row = m0 + wm + mt*16 + (lane>>4)*4 + r;
        int col = n0 + wn + nt*16 + (lane&15);
        float v = acc[mt][nt][r];
        if(EPI==0){
          outb[(size_t)row*N + col] = f2b(v);
        } else if(EPI==1){
          v += bias[col];
          v = 0.5f*v*(1.0f + erff(v*0.70710678118f));
          outb[(size_t)row*N + col] = f2b(v);
        } else if(EPI==2){
          v += bias[col];
          xt[(size_t)row*128 + col] += ls[col]*v;
        } else {
          v += bias[col];
          float rr = xt[(size_t)row*128 + col] + ls[col]*v;
          outb[(size_t)row*128 + col] = f2b(rr);
        }
      }
    }
  }
}

// ---------------- local window attention: seq=64, hd=16, heads 0..3 ----------------
__global__ __launch_bounds__(64) void attn_local(const bf16* __restrict__ qkv,
                                                 bf16* __restrict__ a){
  int idx = blockIdx.x;         // ((b*16+bh)*16+bw)*4 + head
  int head = idx & 3; idx >>= 2;
  int bw = idx & 15; idx >>= 4;
  int bh = idx & 15; int b = idx >> 4;
  int p = threadIdx.x;          // si*8+sj
  int si = p >> 3, sj = p & 7;
  size_t tok = (size_t)b*HW + (size_t)(bh*8+si)*Wl + (bw*8+sj);
  const bf16* base = qkv + tok*384 + head*16;
  __shared__ float Ks[64][16], Vs[64][16];
  float q[16];
#pragma unroll
  for(int d=0;d<16;d++){
    q[d]     = b2f(base[d]);
    Ks[p][d] = b2f(base[128+d]);
    Vs[p][d] = b2f(base[256+d]);
  }
  __syncthreads();
  float m=-1e30f, l=0.f, acc[16]={};
  for(int j=0;j<64;j++){
    float s=0.f;
#pragma unroll
    for(int d=0;d<16;d++) s += q[d]*Ks[j][d];
    s *= 0.25f;
    float mn = fmaxf(m,s);
    float corr = __expf(m-mn);
    float pr   = __expf(s-mn);
    l = l*corr + pr;
#pragma unroll
    for(int d=0;d<16;d++) acc[d] = acc[d]*corr + pr*Vs[j][d];
    m = mn;
  }
  float inv = 1.0f/l;
  bf16* ap = a + tok*Cc + head*16;
#pragma unroll
  for(int d=0;d<16;d++) ap[d] = f2b(acc[d]*inv);
}

// ---------------- grid attention: seq=256 (grid cells), hd=16, heads 4..7 ----------------
__global__ __launch_bounds__(256) void attn_grid(const bf16* __restrict__ qkv,
                                                 bf16* __restrict__ a){
  int idx = blockIdx.x;         // ((b*8+si)*8+sj)*4 + hl
  int hl = idx & 3; idx >>= 2;
  int sj = idx & 7; idx >>= 3;
  int si = idx & 7; int b = idx >> 3;
  int g = threadIdx.x;          // bh*16+bw
  int bh = g >> 4, bw = g & 15;
  size_t tok = (size_t)b*HW + (size_t)(bh*8+si)*Wl + (bw*8+sj);
  const bf16* base = qkv + tok*384 + (4+hl)*16;
  __shared__ float Ks[256][16], Vs[256][16];
  float q[16];
#pragma unroll
  for(int d=0;d<16;d++){
    q[d]     = b2f(base[d]);
    Ks[g][d] = b2f(base[128+d]);
    Vs[g][d] = b2f(base[256+d]);
  }
  __syncthreads();
  float m=-1e30f, l=0.f, acc[16]={};
  for(int j=0;j<256;j++){
    float s=0.f;
#pragma unroll
    for(int d=0;d<16;d++) s += q[d]*Ks[j][d];
    s *= 0.25f;
    float mn = fmaxf(m,s);
    float corr = __expf(m-mn);
    float pr   = __expf(s-mn);
    l = l*corr + pr;
#pragma unroll
    for(int d=0;d<16;d++) acc[d] = acc[d]*corr + pr*Vs[j][d];
    m = mn;
  }
  float inv = 1.0f/l;
  bf16* ap = a + tok*Cc + 64 + hl*16;
#pragma unroll
  for(int d=0;d<16;d++) ap[d] = f2b(acc[d]*inv);
}

// ---------------- (B, HW, C) -> (B, C, HW) transpose, bf16 -> fp32 out ----------------
__global__ __launch_bounds__(256) void transpose_kernel(const bf16* __restrict__ xf,
                                                        float* __restrict__ out){
  __shared__ bf16 tile[32][33];
  int t0 = blockIdx.x*32, c0 = blockIdx.y*32, b = blockIdx.z;
  int x = threadIdx.x, y = threadIdx.y;   // 32, 8
  const bf16* src = xf + (size_t)b*HW*Cc;
  float* dst = out + (size_t)b*Cc*HW;
#pragma unroll
  for(int i=0;i<4;i++)
    tile[y*4+i][x] = src[(size_t)(t0 + y*4+i)*Cc + c0 + x];
  __syncthreads();
#pragma unroll
  for(int i=0;i<4;i++)
    dst[(size_t)(c0 + y*4+i)*HW + t0 + x] = b2f(tile[x][y*4+i]);
}

extern "C" void kernel_launch(void* const* d_in, const int* in_sizes, int n_in,
                              void* d_out, int out_size, void* d_ws, size_t ws_size,
                              hipStream_t stream) {
  const float* x       = (const float*)d_in[0];
  const float* conv_w  = (const float*)d_in[1];
  const float* conv_b  = (const float*)d_in[2];
  const float* norm1_w = (const float*)d_in[3];
  const float* norm1_b = (const float*)d_in[4];
  const float* wqkv    = (const float*)d_in[5];
  const float* proj_w  = (const float*)d_in[6];
  const float* proj_b  = (const float*)d_in[7];
  const float* norm2_w = (const float*)d_in[8];
  const float* norm2_b = (const float*)d_in[9];
  const float* fc1_w   = (const float*)d_in[10];
  const float* fc1_b   = (const float*)d_in[11];
  const float* fc2_w   = (const float*)d_in[12];
  const float* fc2_b   = (const float*)d_in[13];
  const float* ls1     = (const float*)d_in[14];
  const float* ls2     = (const float*)d_in[15];
  float* out = (float*)d_out;

  char* ws = (char*)d_ws;
  float* xt = (float*)ws;                                        // 64 MiB fp32 residual
  bf16*  sh = (bf16*)(ws + (size_t)NT*Cc*4);                     // 32 MiB: xn -> a -> xn2 -> xt_final
  bf16*  qh = (bf16*)(ws + (size_t)NT*Cc*4 + (size_t)NT*Cc*2);   // 128 MiB: qkv then h1
  bf16*  wt = (bf16*)(ws + (size_t)NT*Cc*4 + (size_t)NT*Cc*2 + (size_t)NT*512*2); // 384 KiB
  bf16* qkvT = wt;            // 384 x 128
  bf16* projT= wt + 49152;    // 128 x 128
  bf16* fc1T = wt + 65536;    // 512 x 128
  bf16* fc2T = wt + 131072;   // 128 x 512

  // 0. weight prep (independent of data path)
  transpose_w<<<(128*384+255)/256, 256, 0, stream>>>(wqkv,  qkvT, 128, 384);
  transpose_w<<<(128*128+255)/256, 256, 0, stream>>>(proj_w, projT, 128, 128);
  transpose_w<<<(128*512+255)/256, 256, 0, stream>>>(fc1_w, fc1T, 128, 512);
  transpose_w<<<(512*128+255)/256, 256, 0, stream>>>(fc2_w, fc2T, 512, 128);

  // 1. depthwise conv + bias + residual -> xt (fp32, token-major)
  conv_kernel<<<Bn*Cc*Hh, 128, 0, stream>>>(x, conv_w, conv_b, xt);
  // 2. LN1 -> sh (xn)
  ln_kernel<<<NT/4, 256, 0, stream>>>(xt, norm1_w, norm1_b, sh);
  // 3. qkv = xn @ wqkv  (N x 384)
  mfma_gemm<0><<<dim3(384/64, NT/128), 256, 0, stream>>>(sh, qkvT, nullptr, qh, nullptr, nullptr, 384, 128);
  // 4a. local window attention -> sh channels [0,64)
  attn_local<<<Bn*16*16*4, 64, 0, stream>>>(qh, sh);
  // 4b. grid attention -> sh channels [64,128)
  attn_grid<<<Bn*8*8*4, 256, 0, stream>>>(qh, sh);
  // 5. proj + ls1 residual into xt
  mfma_gemm<2><<<dim3(128/64, NT/128), 256, 0, stream>>>(sh, projT, proj_b, nullptr, xt, ls1, 128, 128);
  // 6. LN2 -> sh (xn2)
  ln_kernel<<<NT/4, 256, 0, stream>>>(xt, norm2_w, norm2_b, sh);
  // 7. fc1 + GELU -> qh (h1, N x 512)
  mfma_gemm<1><<<dim3(512/64, NT/128), 256, 0, stream>>>(sh, fc1T, fc1_b, qh, nullptr, nullptr, 512, 128);
  // 8. fc2 + ls2 residual -> sh (xt_final, bf16 token-major)
  mfma_gemm<3><<<dim3(128/64, NT/128), 256, 0, stream>>>(qh, fc2T, fc2_b, sh, xt, ls2, 128, 512);
  // 9. transpose to (B, C, HW)
  transpose_kernel<<<dim3(HW/32, Cc/32, Bn), dim3(32,8), 0, stream>>>(sh, out);
}

// Round 4
// 723.363 us; speedup vs baseline: 2.1678x; 1.1484x over previous
//
#include <hip/hip_runtime.h>
#include <hip/hip_bf16.h>

typedef __hip_bfloat16 bf16;
typedef __attribute__((ext_vector_type(8))) short short8;
typedef __attribute__((ext_vector_type(4))) float floatx4;

#define Bn 8
#define Cc 128
#define Hh 128
#define Wl 128
#define HW (Hh*Wl)
#define NT (Bn*HW)   // 131072 tokens

__device__ __forceinline__ float b2f(bf16 v){ return __bfloat162float(v); }
__device__ __forceinline__ bf16  f2b(float v){ return __float2bfloat16(v); }

// ---------------- weight cast+transpose: W[K][N] fp32 -> Wt[N][K] bf16 ----------------
__global__ __launch_bounds__(256) void transpose_w(const float* __restrict__ src,
                                                   bf16* __restrict__ dst, int K, int N){
  int idx = blockIdx.x*256 + threadIdx.x;
  if(idx >= K*N) return;
  int n = idx % N, k = idx / N;
  dst[(size_t)n*K + k] = f2b(src[idx]);
}

// ---------------- depthwise 3x3 conv + bias + residual -> channel-last fp32 ----------------
// block = (b, cg, h); 16 channels per block, LDS transpose for coalesced 64B channel-chunk writes
__global__ __launch_bounds__(128) void conv_kernel(const float* __restrict__ x,
                                                   const float* __restrict__ cw,
                                                   const float* __restrict__ cb,
                                                   float* __restrict__ xt){
  __shared__ float tile[16][129];
  int blk = blockIdx.x;              // ((b*8 + cg)*128 + h)
  int h = blk & 127; int t = blk >> 7;
  int cg = t & 7;    int b = t >> 3;
  int w = threadIdx.x;
  for(int ci=0; ci<16; ci++){
    int c = cg*16 + ci;
    const float* xp = x + ((size_t)(b*Cc + c))*HW;
    float wgt[9];
#pragma unroll
    for(int i=0;i<9;i++) wgt[i] = cw[c*9+i];
    float acc = cb[c];
#pragma unroll
    for(int dh=-1; dh<=1; dh++){
      int hh = h+dh;
      if(hh<0 || hh>=Hh) continue;
#pragma unroll
      for(int dw=-1; dw<=1; dw++){
        int ww = w+dw;
        if(ww<0 || ww>=Wl) continue;
        acc += wgt[(dh+1)*3 + (dw+1)] * xp[hh*Wl + ww];
      }
    }
    tile[ci][w] = xp[h*Wl + w] + acc;
  }
  __syncthreads();
  const size_t obase = ((size_t)b*HW + (size_t)h*Wl)*Cc + cg*16;
#pragma unroll
  for(int i=0;i<16;i++){
    int idx = i*128 + threadIdx.x;
    int c2 = idx & 15, w2 = idx >> 4;
    xt[obase + (size_t)w2*Cc + c2] = tile[c2][w2];
  }
}

// ---------------- LayerNorm over C=128, one wave per token ----------------
__global__ __launch_bounds__(256) void ln_kernel(const float* __restrict__ xt,
                                                 const float* __restrict__ wv,
                                                 const float* __restrict__ bv,
                                                 bf16* __restrict__ xn){
  int tok  = blockIdx.x*4 + (threadIdx.x>>6);
  int lane = threadIdx.x & 63;
  const float* row = xt + (size_t)tok*Cc;
  float v0 = row[lane], v1 = row[lane+64];
  float s = v0+v1;
#pragma unroll
  for(int off=32; off; off>>=1) s += __shfl_down(s, off, 64);
  s = __shfl(s, 0, 64);
  float m = s * (1.0f/128.0f);
  float d0 = v0-m, d1 = v1-m;
  float vs = d0*d0 + d1*d1;
#pragma unroll
  for(int off=32; off; off>>=1) vs += __shfl_down(vs, off, 64);
  vs = __shfl(vs, 0, 64);
  float rstd = rsqrtf(vs*(1.0f/128.0f) + 1e-5f);
  bf16* orow = xn + (size_t)tok*Cc;
  orow[lane]    = f2b(d0*rstd*wv[lane]    + bv[lane]);
  orow[lane+64] = f2b(d1*rstd*wv[lane+64] + bv[lane+64]);
}

// ---------------- MFMA bf16 GEMM: C[M][N] = A[M][K] @ W[K][N], Wt[N][K] given ----------------
template<int EPI>
__global__ __launch_bounds__(256) void mfma_gemm(const bf16* __restrict__ A,
                                                 const bf16* __restrict__ Wt,
                                                 const float* __restrict__ bias,
                                                 bf16* __restrict__ outb,
                                                 float* __restrict__ xt,
                                                 const float* __restrict__ ls,
                                                 int N, int K){
  __shared__ short As[128*32];   // [mtile8][quad4][m16][8]
  __shared__ short Bs[64*32];    // [ntile4][quad4][n16][8]
  const int m0 = blockIdx.y*128, n0 = blockIdx.x*64;
  const int tid = threadIdx.x;
  const int lane = tid & 63;
  const int w = tid >> 6;
  const int wm = (w&1)*64;
  const int wn = (w>>1)*32;

  floatx4 acc[4][2];
#pragma unroll
  for(int i=0;i<4;i++)
#pragma unroll
    for(int j=0;j<2;j++) acc[i][j] = (floatx4){0.f,0.f,0.f,0.f};

  for(int k0=0; k0<K; k0+=32){
#pragma unroll
    for(int p=0;p<2;p++){
      int ch = tid + p*256;
      int r = ch & 127, c = ch >> 7;
      short8 v = *(const short8*)(A + (size_t)(m0+r)*K + k0 + c*8);
      int lidx = ((r>>4)*4 + c)*16 + (r&15);
      *(short8*)&As[lidx*8] = v;
    }
    {
      int n = tid & 63, c = tid >> 6;
      short8 v = *(const short8*)(Wt + (size_t)(n0+n)*K + k0 + c*8);
      int lidx = ((n>>4)*4 + c)*16 + (n&15);
      *(short8*)&Bs[lidx*8] = v;
    }
    __syncthreads();
    short8 af[4], bfr[2];
#pragma unroll
    for(int mt=0;mt<4;mt++) af[mt] = *(short8*)&As[(((w&1)*4+mt)*64 + lane)*8];
#pragma unroll
    for(int nt=0;nt<2;nt++) bfr[nt] = *(short8*)&Bs[(((w>>1)*2+nt)*64 + lane)*8];
#pragma unroll
    for(int mt=0;mt<4;mt++)
#pragma unroll
      for(int nt=0;nt<2;nt++)
        acc[mt][nt] = __builtin_amdgcn_mfma_f32_16x16x32_bf16(af[mt], bfr[nt], acc[mt][nt], 0, 0, 0);
    __syncthreads();
  }

#pragma unroll
  for(int mt=0;mt<4;mt++){
#pragma unroll
    for(int nt=0;nt<2;nt++){
#pragma unroll
      for(int r=0;r<4;r++){
        int row = m0 + wm + mt*16 + ((lane>>4))*4 + r;
        int col = n0 + wn + nt*16 + (lane&15);
        float v = acc[mt][nt][r];
        if(EPI==0){
          outb[(size_t)row*N + col] = f2b(v);
        } else if(EPI==1){
          v += bias[col];
          v = 0.5f*v*(1.0f + erff(v*0.70710678118f));
          outb[(size_t)row*N + col] = f2b(v);
        } else if(EPI==2){
          v += bias[col];
          xt[(size_t)row*128 + col] += ls[col]*v;
        } else {
          v += bias[col];
          float rr = xt[(size_t)row*128 + col] + ls[col]*v;
          outb[(size_t)row*128 + col] = f2b(rr);
        }
      }
    }
  }
}

// ---------------- MFMA flash attention ----------------
// One workgroup per instance, one wave per head. L = sequence length (64 local / 256 grid).
// hd=16 padded to K=32 for QK^T (quads 2,3 zero). K-frags & V-frags live in registers.
// Per-wave LDS buffer: V-transpose staging, then P (C-layout -> A-layout round trip).
template<int L, int GRID>
__global__ __launch_bounds__(256, 2) void attn_mfma(const bf16* __restrict__ qkv,
                                                    bf16* __restrict__ a){
  constexpr int NTILE = L/16;     // 16-col S tiles
  constexpr int NKB   = L/32;     // 32-k PV blocks
  constexpr int PS    = L + 12;   // padded LDS row stride (elements)
  __shared__ short lds[4][16*PS];
  const int tid = threadIdx.x;
  const int w = tid >> 6, lane = tid & 63;
  const int n16 = lane & 15, quad = lane >> 4;
  short* buf = &lds[w][0];

  const int blk = blockIdx.x;
  int b, r0, c0;
  if(GRID){ b = blk >> 6; r0 = (blk>>3)&7; c0 = blk&7; }       // (b, si, sj)
  else    { b = blk >> 8; r0 = (blk>>4)&15; c0 = blk&15; }     // (b, bh, bw)
  const int head = GRID ? (4+w) : w;
  const int qoff = head*16, koff = 128 + head*16, voff = 256 + head*16;
  const int ooff = head*16;

  auto tokof = [&](int g)->size_t{
    int hh, ww;
    if(GRID){ hh = (g>>4)*8 + r0; ww = (g&15)*8 + c0; }
    else    { hh = r0*8 + (g>>3); ww = c0*8 + (g&7); }
    return (size_t)b*HW + (size_t)hh*Wl + ww;
  };

  // ---- K fragments (registers, quads 2,3 zero-padded) ----
  short8 kf[NTILE];
#pragma unroll
  for(int kt=0; kt<NTILE; kt++){
    short8 v = {0,0,0,0,0,0,0,0};
    if(quad < 2) v = *(const short8*)(qkv + tokof(kt*16 + n16)*384 + koff + quad*8);
    kf[kt] = v;
  }

  // ---- V transpose through LDS, then B-fragments into registers ----
#pragma unroll
  for(int it=0; it<L/32; it++){
    int chunk = it*64 + lane;          // (t, u)
    int t = chunk >> 1, u = chunk & 1;
    short8 v = *(const short8*)(qkv + tokof(t)*384 + voff + u*8);
#pragma unroll
    for(int i=0;i<8;i++) buf[(u*8+i)*PS + t] = ((short*)&v)[i];
  }
  short8 vf[NKB];
#pragma unroll
  for(int kb=0; kb<NKB; kb++)
    vf[kb] = *(short8*)&buf[n16*PS + kb*32 + quad*8];

  // ---- Q-tile loop ----
  for(int qt=0; qt<NTILE; qt++){
    short8 qf = {0,0,0,0,0,0,0,0};
    if(quad < 2) qf = *(const short8*)(qkv + tokof(qt*16 + n16)*384 + qoff + quad*8);

    floatx4 sf[NTILE];
#pragma unroll
    for(int kt=0; kt<NTILE; kt++){
      floatx4 z = (floatx4){0.f,0.f,0.f,0.f};
      sf[kt] = __builtin_amdgcn_mfma_f32_16x16x32_bf16(qf, kf[kt], z, 0, 0, 0);
    }

    // row max over L cols (rows m = quad*4 + r)
    float mx[4] = {-1e30f,-1e30f,-1e30f,-1e30f};
#pragma unroll
    for(int kt=0; kt<NTILE; kt++)
#pragma unroll
      for(int r=0;r<4;r++) mx[r] = fmaxf(mx[r], sf[kt][r]);
#pragma unroll
    for(int r=0;r<4;r++){
      mx[r] = fmaxf(mx[r], __shfl_xor(mx[r], 1, 64));
      mx[r] = fmaxf(mx[r], __shfl_xor(mx[r], 2, 64));
      mx[r] = fmaxf(mx[r], __shfl_xor(mx[r], 4, 64));
      mx[r] = fmaxf(mx[r], __shfl_xor(mx[r], 8, 64));
    }
    // exp + row sum; write P (bf16, packed pairs) into LDS
    float l[4] = {0.f,0.f,0.f,0.f};
#pragma unroll
    for(int kt=0; kt<NTILE; kt++){
#pragma unroll
      for(int r=0;r<4;r++){
        float p = __expf((sf[kt][r] - mx[r])*0.25f);
        l[r] += p;
        bf16 pb = f2b(p);
        int mi = (int)(*(unsigned short*)&pb);
        int oi = __shfl_xor(mi, 1, 64);
        if(!(n16 & 1)){
          unsigned pk = (unsigned)mi | ((unsigned)oi << 16);
          *(unsigned*)&buf[(quad*4+r)*PS + kt*16 + n16] = pk;
        }
      }
    }
#pragma unroll
    for(int r=0;r<4;r++){
      l[r] += __shfl_xor(l[r], 1, 64);
      l[r] += __shfl_xor(l[r], 2, 64);
      l[r] += __shfl_xor(l[r], 4, 64);
      l[r] += __shfl_xor(l[r], 8, 64);
    }

    // PV: A = P (from LDS), B = V (registers)
    floatx4 of = (floatx4){0.f,0.f,0.f,0.f};
#pragma unroll
    for(int kb=0; kb<NKB; kb++){
      short8 pf = *(short8*)&buf[n16*PS + kb*32 + quad*8];
      of = __builtin_amdgcn_mfma_f32_16x16x32_bf16(pf, vf[kb], of, 0, 0, 0);
    }

    // store O: row = quad*4+r, col = n16
#pragma unroll
    for(int r=0;r<4;r++){
      size_t t = tokof(qt*16 + quad*4 + r);
      a[t*Cc + ooff + n16] = f2b(of[r] / l[r]);
    }
  }
}

// ---------------- (B, HW, C) -> (B, C, HW) transpose, bf16 -> fp32 out ----------------
__global__ __launch_bounds__(256) void transpose_kernel(const bf16* __restrict__ xf,
                                                        float* __restrict__ out){
  __shared__ bf16 tile[32][33];
  int t0 = blockIdx.x*32, c0 = blockIdx.y*32, b = blockIdx.z;
  int x = threadIdx.x, y = threadIdx.y;   // 32, 8
  const bf16* src = xf + (size_t)b*HW*Cc;
  float* dst = out + (size_t)b*Cc*HW;
#pragma unroll
  for(int i=0;i<4;i++)
    tile[y*4+i][x] = src[(size_t)(t0 + y*4+i)*Cc + c0 + x];
  __syncthreads();
#pragma unroll
  for(int i=0;i<4;i++)
    dst[(size_t)(c0 + y*4+i)*HW + t0 + x] = b2f(tile[x][y*4+i]);
}

extern "C" void kernel_launch(void* const* d_in, const int* in_sizes, int n_in,
                              void* d_out, int out_size, void* d_ws, size_t ws_size,
                              hipStream_t stream) {
  const float* x       = (const float*)d_in[0];
  const float* conv_w  = (const float*)d_in[1];
  const float* conv_b  = (const float*)d_in[2];
  const float* norm1_w = (const float*)d_in[3];
  const float* norm1_b = (const float*)d_in[4];
  const float* wqkv    = (const float*)d_in[5];
  const float* proj_w  = (const float*)d_in[6];
  const float* proj_b  = (const float*)d_in[7];
  const float* norm2_w = (const float*)d_in[8];
  const float* norm2_b = (const float*)d_in[9];
  const float* fc1_w   = (const float*)d_in[10];
  const float* fc1_b   = (const float*)d_in[11];
  const float* fc2_w   = (const float*)d_in[12];
  const float* fc2_b   = (const float*)d_in[13];
  const float* ls1     = (const float*)d_in[14];
  const float* ls2     = (const float*)d_in[15];
  float* out = (float*)d_out;

  char* ws = (char*)d_ws;
  float* xt = (float*)ws;                                        // 64 MiB fp32 residual
  bf16*  sh = (bf16*)(ws + (size_t)NT*Cc*4);                     // 32 MiB: xn -> a -> xn2 -> xt_final
  bf16*  qh = (bf16*)(ws + (size_t)NT*Cc*4 + (size_t)NT*Cc*2);   // 128 MiB: qkv then h1
  bf16*  wt = (bf16*)(ws + (size_t)NT*Cc*4 + (size_t)NT*Cc*2 + (size_t)NT*512*2);
  bf16* qkvT = wt;            // 384 x 128
  bf16* projT= wt + 49152;    // 128 x 128
  bf16* fc1T = wt + 65536;    // 512 x 128
  bf16* fc2T = wt + 131072;   // 128 x 512

  transpose_w<<<(128*384+255)/256, 256, 0, stream>>>(wqkv,  qkvT, 128, 384);
  transpose_w<<<(128*128+255)/256, 256, 0, stream>>>(proj_w, projT, 128, 128);
  transpose_w<<<(128*512+255)/256, 256, 0, stream>>>(fc1_w, fc1T, 128, 512);
  transpose_w<<<(512*128+255)/256, 256, 0, stream>>>(fc2_w, fc2T, 512, 128);

  conv_kernel<<<Bn*8*Hh, 128, 0, stream>>>(x, conv_w, conv_b, xt);
  ln_kernel<<<NT/4, 256, 0, stream>>>(xt, norm1_w, norm1_b, sh);
  mfma_gemm<0><<<dim3(384/64, NT/128), 256, 0, stream>>>(sh, qkvT, nullptr, qh, nullptr, nullptr, 384, 128);
  attn_mfma<64,0><<<Bn*16*16, 256, 0, stream>>>(qh, sh);
  attn_mfma<256,1><<<Bn*8*8, 256, 0, stream>>>(qh, sh);
  mfma_gemm<2><<<dim3(128/64, NT/128), 256, 0, stream>>>(sh, projT, proj_b, nullptr, xt, ls1, 128, 128);
  ln_kernel<<<NT/4, 256, 0, stream>>>(xt, norm2_w, norm2_b, sh);
  mfma_gemm<1><<<dim3(512/64, NT/128), 256, 0, stream>>>(sh, fc1T, fc1_b, qh, nullptr, nullptr, 512, 128);
  mfma_gemm<3><<<dim3(128/64, NT/128), 256, 0, stream>>>(qh, fc2T, fc2_b, sh, xt, ls2, 128, 512);
  transpose_kernel<<<dim3(HW/32, Cc/32, Bn), dim3(32,8), 0, stream>>>(sh, out);
}

// Round 5
// 615.200 us; speedup vs baseline: 2.5490x; 1.1758x over previous
//
#include <hip/hip_runtime.h>
#include <hip/hip_bf16.h>

typedef __hip_bfloat16 bf16;
typedef __attribute__((ext_vector_type(8))) short short8;
typedef __attribute__((ext_vector_type(4))) float floatx4;

#define Bn 8
#define Cc 128
#define Hh 128
#define Wl 128
#define HW (Hh*Wl)
#define NT (Bn*HW)   // 131072 tokens

__device__ __forceinline__ float b2f(bf16 v){ return __bfloat162float(v); }
__device__ __forceinline__ bf16  f2b(float v){ return __float2bfloat16(v); }

// ---------------- all weight transposes in one launch ----------------
// dst layouts: qkvT[384][128], projT[128][128], fc1T[512][128], fc2T[128][512]
__global__ __launch_bounds__(256) void transpose_all(const float* __restrict__ wqkv,
                                                     const float* __restrict__ proj_w,
                                                     const float* __restrict__ fc1_w,
                                                     const float* __restrict__ fc2_w,
                                                     bf16* __restrict__ qkvT,
                                                     bf16* __restrict__ projT,
                                                     bf16* __restrict__ fc1T,
                                                     bf16* __restrict__ fc2T){
  int idx = blockIdx.x*256 + threadIdx.x;
  const float* src; bf16* dst; int K, N;
  if(idx < 49152){ src=wqkv; dst=qkvT; K=128; N=384; }
  else if(idx < 65536){ idx -= 49152; src=proj_w; dst=projT; K=128; N=128; }
  else if(idx < 131072){ idx -= 65536; src=fc1_w; dst=fc1T; K=128; N=512; }
  else { idx -= 131072; src=fc2_w; dst=fc2T; K=512; N=128; }
  int n = idx % N, k = idx / N;
  dst[(size_t)n*K + k] = f2b(src[idx]);
}

// ---------------- depthwise 3x3 conv + bias + residual -> channel-last fp32 ----------------
// block = (b, cg, h); 256 thr = 32 w-quads x 8 ch-slots; 2 channels/thread; float4 + shfl stencil
__global__ __launch_bounds__(256) void conv_kernel(const float* __restrict__ x,
                                                   const float* __restrict__ cw,
                                                   const float* __restrict__ cb,
                                                   float* __restrict__ xt){
  __shared__ float tile[16][132];
  int blk = blockIdx.x;              // ((b*8 + cg)*128 + h)
  int h = blk & 127; int t = blk >> 7;
  int cg = t & 7;    int b = t >> 3;
  int w4 = threadIdx.x & 31;         // float4 index along w
  int ci = threadIdx.x >> 5;         // 0..7
  int w0 = w4*4;
#pragma unroll
  for(int cc=0; cc<2; cc++){
    int c = cg*16 + ci*2 + cc;
    const float* xp = x + ((size_t)(b*Cc + c))*HW;
    float wg[9];
#pragma unroll
    for(int i=0;i<9;i++) wg[i] = cw[c*9+i];
    float4 rowv[3]; float lf[3], rt[3];
#pragma unroll
    for(int r=0;r<3;r++){
      int hh = h-1+r;
      float4 v = {0.f,0.f,0.f,0.f};
      if(hh>=0 && hh<Hh) v = *(const float4*)(xp + hh*Wl + w0);
      rowv[r] = v;
      float l = __shfl_up(v.w, 1, 32);
      float rr = __shfl_down(v.x, 1, 32);
      lf[r] = (w4==0)  ? 0.f : l;
      rt[r] = (w4==31) ? 0.f : rr;
    }
    float acc0 = cb[c], acc1 = cb[c], acc2 = cb[c], acc3 = cb[c];
#pragma unroll
    for(int r=0;r<3;r++){
      float4 v = rowv[r];
      acc0 += wg[r*3+0]*lf[r] + wg[r*3+1]*v.x + wg[r*3+2]*v.y;
      acc1 += wg[r*3+0]*v.x   + wg[r*3+1]*v.y + wg[r*3+2]*v.z;
      acc2 += wg[r*3+0]*v.y   + wg[r*3+1]*v.z + wg[r*3+2]*v.w;
      acc3 += wg[r*3+0]*v.z   + wg[r*3+1]*v.w + wg[r*3+2]*rt[r];
    }
    // residual (center row)
    acc0 += rowv[1].x; acc1 += rowv[1].y; acc2 += rowv[1].z; acc3 += rowv[1].w;
    float4 o = {acc0, acc1, acc2, acc3};
    *(float4*)&tile[ci*2+cc][w0] = o;
  }
  __syncthreads();
  const size_t obase = ((size_t)b*HW + (size_t)h*Wl)*Cc + cg*16;
#pragma unroll
  for(int i=0;i<8;i++){
    int idx = i*256 + threadIdx.x;
    int c2 = idx & 15, w2 = idx >> 4;
    xt[obase + (size_t)w2*Cc + c2] = tile[c2][w2];
  }
}

// ---------------- LayerNorm over C=128, one wave per token ----------------
__global__ __launch_bounds__(256) void ln_kernel(const float* __restrict__ xt,
                                                 const float* __restrict__ wv,
                                                 const float* __restrict__ bv,
                                                 bf16* __restrict__ xn){
  int tok  = blockIdx.x*4 + (threadIdx.x>>6);
  int lane = threadIdx.x & 63;
  const float* row = xt + (size_t)tok*Cc;
  float v0 = row[lane], v1 = row[lane+64];
  float s = v0+v1;
#pragma unroll
  for(int off=32; off; off>>=1) s += __shfl_down(s, off, 64);
  s = __shfl(s, 0, 64);
  float m = s * (1.0f/128.0f);
  float d0 = v0-m, d1 = v1-m;
  float vs = d0*d0 + d1*d1;
#pragma unroll
  for(int off=32; off; off>>=1) vs += __shfl_down(vs, off, 64);
  vs = __shfl(vs, 0, 64);
  float rstd = rsqrtf(vs*(1.0f/128.0f) + 1e-5f);
  bf16* orow = xn + (size_t)tok*Cc;
  orow[lane]    = f2b(d0*rstd*wv[lane]    + bv[lane]);
  orow[lane+64] = f2b(d1*rstd*wv[lane+64] + bv[lane+64]);
}

// ---------------- MFMA bf16 GEMM: C[M][N] = A[M][K] @ W[K][N], Wt[N][K] given ----------------
template<int EPI>
__global__ __launch_bounds__(256) void mfma_gemm(const bf16* __restrict__ A,
                                                 const bf16* __restrict__ Wt,
                                                 const float* __restrict__ bias,
                                                 bf16* __restrict__ outb,
                                                 float* __restrict__ xt,
                                                 const float* __restrict__ ls,
                                                 int N, int K){
  __shared__ short As[128*32];   // [mtile8][quad4][m16][8]
  __shared__ short Bs[64*32];    // [ntile4][quad4][n16][8]
  const int m0 = blockIdx.y*128, n0 = blockIdx.x*64;
  const int tid = threadIdx.x;
  const int lane = tid & 63;
  const int w = tid >> 6;

  floatx4 acc[4][2];
#pragma unroll
  for(int i=0;i<4;i++)
#pragma unroll
    for(int j=0;j<2;j++) acc[i][j] = (floatx4){0.f,0.f,0.f,0.f};

  for(int k0=0; k0<K; k0+=32){
#pragma unroll
    for(int p=0;p<2;p++){
      int ch = tid + p*256;
      int r = ch & 127, c = ch >> 7;
      short8 v = *(const short8*)(A + (size_t)(m0+r)*K + k0 + c*8);
      int lidx = ((r>>4)*4 + c)*16 + (r&15);
      *(short8*)&As[lidx*8] = v;
    }
    {
      int n = tid & 63, c = tid >> 6;
      short8 v = *(const short8*)(Wt + (size_t)(n0+n)*K + k0 + c*8);
      int lidx = ((n>>4)*4 + c)*16 + (n&15);
      *(short8*)&Bs[lidx*8] = v;
    }
    __syncthreads();
    short8 af[4], bfr[2];
#pragma unroll
    for(int mt=0;mt<4;mt++) af[mt] = *(short8*)&As[(((w&1)*4+mt)*64 + lane)*8];
#pragma unroll
    for(int nt=0;nt<2;nt++) bfr[nt] = *(short8*)&Bs[(((w>>1)*2+nt)*64 + lane)*8];
#pragma unroll
    for(int mt=0;mt<4;mt++)
#pragma unroll
      for(int nt=0;nt<2;nt++)
        acc[mt][nt] = __builtin_amdgcn_mfma_f32_16x16x32_bf16(af[mt], bfr[nt], acc[mt][nt], 0, 0, 0);
    __syncthreads();
  }

#pragma unroll
  for(int mt=0;mt<4;mt++){
#pragma unroll
    for(int nt=0;nt<2;nt++){
#pragma unroll
      for(int r=0;r<4;r++){
        int row = m0 + (w&1)*64 + mt*16 + ((lane>>4))*4 + r;
        int col = n0 + (w>>1)*32 + nt*16 + (lane&15);
        float v = acc[mt][nt][r];
        if(EPI==0){
          outb[(size_t)row*N + col] = f2b(v);
        } else if(EPI==1){
          v += bias[col];
          v = 0.5f*v*(1.0f + erff(v*0.70710678118f));
          outb[(size_t)row*N + col] = f2b(v);
        } else if(EPI==2){
          v += bias[col];
          xt[(size_t)row*128 + col] += ls[col]*v;
        } else {
          v += bias[col];
          float rr = xt[(size_t)row*128 + col] + ls[col]*v;
          outb[(size_t)row*128 + col] = f2b(rr);
        }
      }
    }
  }
}

// ---------------- MFMA flash attention ----------------
template<int L, int GRID>
__global__ __launch_bounds__(256, 2) void attn_mfma(const bf16* __restrict__ qkv,
                                                    bf16* __restrict__ a){
  constexpr int NTILE = L/16;
  constexpr int NKB   = L/32;
  constexpr int PS    = L + 12;
  __shared__ short lds[4][16*PS];
  const int tid = threadIdx.x;
  const int w = tid >> 6, lane = tid & 63;
  const int n16 = lane & 15, quad = lane >> 4;
  short* buf = &lds[w][0];

  const int blk = blockIdx.x;
  int b, r0, c0;
  if(GRID){ b = blk >> 6; r0 = (blk>>3)&7; c0 = blk&7; }
  else    { b = blk >> 8; r0 = (blk>>4)&15; c0 = blk&15; }
  const int head = GRID ? (4+w) : w;
  const int qoff = head*16, koff = 128 + head*16, voff = 256 + head*16;
  const int ooff = head*16;

  auto tokof = [&](int g)->size_t{
    int hh, ww;
    if(GRID){ hh = (g>>4)*8 + r0; ww = (g&15)*8 + c0; }
    else    { hh = r0*8 + (g>>3); ww = c0*8 + (g&7); }
    return (size_t)b*HW + (size_t)hh*Wl + ww;
  };

  short8 kf[NTILE];
#pragma unroll
  for(int kt=0; kt<NTILE; kt++){
    short8 v = {0,0,0,0,0,0,0,0};
    if(quad < 2) v = *(const short8*)(qkv + tokof(kt*16 + n16)*384 + koff + quad*8);
    kf[kt] = v;
  }

#pragma unroll
  for(int it=0; it<L/32; it++){
    int chunk = it*64 + lane;
    int t = chunk >> 1, u = chunk & 1;
    short8 v = *(const short8*)(qkv + tokof(t)*384 + voff + u*8);
#pragma unroll
    for(int i=0;i<8;i++) buf[(u*8+i)*PS + t] = ((short*)&v)[i];
  }
  short8 vf[NKB];
#pragma unroll
  for(int kb=0; kb<NKB; kb++)
    vf[kb] = *(short8*)&buf[n16*PS + kb*32 + quad*8];

  for(int qt=0; qt<NTILE; qt++){
    short8 qf = {0,0,0,0,0,0,0,0};
    if(quad < 2) qf = *(const short8*)(qkv + tokof(qt*16 + n16)*384 + qoff + quad*8);

    floatx4 sf[NTILE];
#pragma unroll
    for(int kt=0; kt<NTILE; kt++){
      floatx4 z = (floatx4){0.f,0.f,0.f,0.f};
      sf[kt] = __builtin_amdgcn_mfma_f32_16x16x32_bf16(qf, kf[kt], z, 0, 0, 0);
    }

    float mx[4] = {-1e30f,-1e30f,-1e30f,-1e30f};
#pragma unroll
    for(int kt=0; kt<NTILE; kt++)
#pragma unroll
      for(int r=0;r<4;r++) mx[r] = fmaxf(mx[r], sf[kt][r]);
#pragma unroll
    for(int r=0;r<4;r++){
      mx[r] = fmaxf(mx[r], __shfl_xor(mx[r], 1, 64));
      mx[r] = fmaxf(mx[r], __shfl_xor(mx[r], 2, 64));
      mx[r] = fmaxf(mx[r], __shfl_xor(mx[r], 4, 64));
      mx[r] = fmaxf(mx[r], __shfl_xor(mx[r], 8, 64));
    }
    float l[4] = {0.f,0.f,0.f,0.f};
#pragma unroll
    for(int kt=0; kt<NTILE; kt++){
#pragma unroll
      for(int r=0;r<4;r++){
        float p = __expf((sf[kt][r] - mx[r])*0.25f);
        l[r] += p;
        bf16 pb = f2b(p);
        int mi = (int)(*(unsigned short*)&pb);
        int oi = __shfl_xor(mi, 1, 64);
        if(!(n16 & 1)){
          unsigned pk = (unsigned)mi | ((unsigned)oi << 16);
          *(unsigned*)&buf[(quad*4+r)*PS + kt*16 + n16] = pk;
        }
      }
    }
#pragma unroll
    for(int r=0;r<4;r++){
      l[r] += __shfl_xor(l[r], 1, 64);
      l[r] += __shfl_xor(l[r], 2, 64);
      l[r] += __shfl_xor(l[r], 4, 64);
      l[r] += __shfl_xor(l[r], 8, 64);
    }

    floatx4 of = (floatx4){0.f,0.f,0.f,0.f};
#pragma unroll
    for(int kb=0; kb<NKB; kb++){
      short8 pf = *(short8*)&buf[n16*PS + kb*32 + quad*8];
      of = __builtin_amdgcn_mfma_f32_16x16x32_bf16(pf, vf[kb], of, 0, 0, 0);
    }

#pragma unroll
    for(int r=0;r<4;r++){
      size_t t = tokof(qt*16 + quad*4 + r);
      a[t*Cc + ooff + n16] = f2b(of[r] / l[r]);
    }
  }
}

// ---------------- (B, HW, C) -> (B, C, HW) transpose, bf16 -> fp32 out ----------------
__global__ __launch_bounds__(256) void transpose_kernel(const bf16* __restrict__ xf,
                                                        float* __restrict__ out){
  __shared__ bf16 tile[32][33];
  int t0 = blockIdx.x*32, c0 = blockIdx.y*32, b = blockIdx.z;
  int x = threadIdx.x, y = threadIdx.y;   // 32, 8
  const bf16* src = xf + (size_t)b*HW*Cc;
  float* dst = out + (size_t)b*Cc*HW;
#pragma unroll
  for(int i=0;i<4;i++)
    tile[y*4+i][x] = src[(size_t)(t0 + y*4+i)*Cc + c0 + x];
  __syncthreads();
#pragma unroll
  for(int i=0;i<4;i++)
    dst[(size_t)(c0 + y*4+i)*HW + t0 + x] = b2f(tile[x][y*4+i]);
}

extern "C" void kernel_launch(void* const* d_in, const int* in_sizes, int n_in,
                              void* d_out, int out_size, void* d_ws, size_t ws_size,
                              hipStream_t stream) {
  const float* x       = (const float*)d_in[0];
  const float* conv_w  = (const float*)d_in[1];
  const float* conv_b  = (const float*)d_in[2];
  const float* norm1_w = (const float*)d_in[3];
  const float* norm1_b = (const float*)d_in[4];
  const float* wqkv    = (const float*)d_in[5];
  const float* proj_w  = (const float*)d_in[6];
  const float* proj_b  = (const float*)d_in[7];
  const float* norm2_w = (const float*)d_in[8];
  const float* norm2_b = (const float*)d_in[9];
  const float* fc1_w   = (const float*)d_in[10];
  const float* fc1_b   = (const float*)d_in[11];
  const float* fc2_w   = (const float*)d_in[12];
  const float* fc2_b   = (const float*)d_in[13];
  const float* ls1     = (const float*)d_in[14];
  const float* ls2     = (const float*)d_in[15];
  float* out = (float*)d_out;

  char* ws = (char*)d_ws;
  float* xt = (float*)ws;                                        // 64 MiB fp32 residual
  bf16*  sh = (bf16*)(ws + (size_t)NT*Cc*4);                     // 32 MiB: xn -> a -> xn2 -> xt_final
  bf16*  qh = (bf16*)(ws + (size_t)NT*Cc*4 + (size_t)NT*Cc*2);   // 128 MiB: qkv then h1
  bf16*  wt = (bf16*)(ws + (size_t)NT*Cc*4 + (size_t)NT*Cc*2 + (size_t)NT*512*2);
  bf16* qkvT = wt;            // 384 x 128
  bf16* projT= wt + 49152;    // 128 x 128
  bf16* fc1T = wt + 65536;    // 512 x 128
  bf16* fc2T = wt + 131072;   // 128 x 512

  transpose_all<<<196608/256, 256, 0, stream>>>(wqkv, proj_w, fc1_w, fc2_w,
                                                qkvT, projT, fc1T, fc2T);
  conv_kernel<<<Bn*8*Hh, 256, 0, stream>>>(x, conv_w, conv_b, xt);
  ln_kernel<<<NT/4, 256, 0, stream>>>(xt, norm1_w, norm1_b, sh);
  mfma_gemm<0><<<dim3(384/64, NT/128), 256, 0, stream>>>(sh, qkvT, nullptr, qh, nullptr, nullptr, 384, 128);
  attn_mfma<64,0><<<Bn*16*16, 256, 0, stream>>>(qh, sh);
  attn_mfma<256,1><<<Bn*8*8, 256, 0, stream>>>(qh, sh);
  mfma_gemm<2><<<dim3(128/64, NT/128), 256, 0, stream>>>(sh, projT, proj_b, nullptr, xt, ls1, 128, 128);
  ln_kernel<<<NT/4, 256, 0, stream>>>(xt, norm2_w, norm2_b, sh);
  mfma_gemm<1><<<dim3(512/64, NT/128), 256, 0, stream>>>(sh, fc1T, fc1_b, qh, nullptr, nullptr, 512, 128);
  mfma_gemm<3><<<dim3(128/64, NT/128), 256, 0, stream>>>(qh, fc2T, fc2_b, sh, xt, ls2, 128, 512);
  transpose_kernel<<<dim3(HW/32, Cc/32, Bn), dim3(32,8), 0, stream>>>(sh, out);
}

// Round 6
// 594.738 us; speedup vs baseline: 2.6367x; 1.0344x over previous
//
#include <hip/hip_runtime.h>
#include <hip/hip_bf16.h>

typedef __hip_bfloat16 bf16;
typedef __attribute__((ext_vector_type(8))) short short8;
typedef __attribute__((ext_vector_type(4))) float floatx4;

#define Bn 8
#define Cc 128
#define Hh 128
#define Wl 128
#define HW (Hh*Wl)
#define NT (Bn*HW)   // 131072 tokens

__device__ __forceinline__ float b2f(bf16 v){ return __bfloat162float(v); }
__device__ __forceinline__ bf16  f2b(float v){ return __float2bfloat16(v); }

// ---------------- all weight transposes in one launch ----------------
__global__ __launch_bounds__(256) void transpose_all(const float* __restrict__ wqkv,
                                                     const float* __restrict__ proj_w,
                                                     const float* __restrict__ fc1_w,
                                                     const float* __restrict__ fc2_w,
                                                     bf16* __restrict__ qkvT,
                                                     bf16* __restrict__ projT,
                                                     bf16* __restrict__ fc1T,
                                                     bf16* __restrict__ fc2T){
  int idx = blockIdx.x*256 + threadIdx.x;
  const float* src; bf16* dst; int K, N;
  if(idx < 49152){ src=wqkv; dst=qkvT; K=128; N=384; }
  else if(idx < 65536){ idx -= 49152; src=proj_w; dst=projT; K=128; N=128; }
  else if(idx < 131072){ idx -= 65536; src=fc1_w; dst=fc1T; K=128; N=512; }
  else { idx -= 131072; src=fc2_w; dst=fc2T; K=512; N=128; }
  int n = idx % N, k = idx / N;
  dst[(size_t)n*K + k] = f2b(src[idx]);
}

// ---------------- depthwise 3x3 conv + bias + residual -> channel-last fp32 ----------------
__global__ __launch_bounds__(256) void conv_kernel(const float* __restrict__ x,
                                                   const float* __restrict__ cw,
                                                   const float* __restrict__ cb,
                                                   float* __restrict__ xt){
  __shared__ float tile[16][132];
  int blk = blockIdx.x;              // ((b*8 + cg)*128 + h)
  int h = blk & 127; int t = blk >> 7;
  int cg = t & 7;    int b = t >> 3;
  int w4 = threadIdx.x & 31;         // float4 index along w
  int ci = threadIdx.x >> 5;         // 0..7
  int w0 = w4*4;
#pragma unroll
  for(int cc=0; cc<2; cc++){
    int c = cg*16 + ci*2 + cc;
    const float* xp = x + ((size_t)(b*Cc + c))*HW;
    float wg[9];
#pragma unroll
    for(int i=0;i<9;i++) wg[i] = cw[c*9+i];
    float4 rowv[3]; float lf[3], rt[3];
#pragma unroll
    for(int r=0;r<3;r++){
      int hh = h-1+r;
      float4 v = {0.f,0.f,0.f,0.f};
      if(hh>=0 && hh<Hh) v = *(const float4*)(xp + hh*Wl + w0);
      rowv[r] = v;
      float l = __shfl_up(v.w, 1, 32);
      float rr = __shfl_down(v.x, 1, 32);
      lf[r] = (w4==0)  ? 0.f : l;
      rt[r] = (w4==31) ? 0.f : rr;
    }
    float acc0 = cb[c], acc1 = cb[c], acc2 = cb[c], acc3 = cb[c];
#pragma unroll
    for(int r=0;r<3;r++){
      float4 v = rowv[r];
      acc0 += wg[r*3+0]*lf[r] + wg[r*3+1]*v.x + wg[r*3+2]*v.y;
      acc1 += wg[r*3+0]*v.x   + wg[r*3+1]*v.y + wg[r*3+2]*v.z;
      acc2 += wg[r*3+0]*v.y   + wg[r*3+1]*v.z + wg[r*3+2]*v.w;
      acc3 += wg[r*3+0]*v.z   + wg[r*3+1]*v.w + wg[r*3+2]*rt[r];
    }
    acc0 += rowv[1].x; acc1 += rowv[1].y; acc2 += rowv[1].z; acc3 += rowv[1].w;
    float4 o = {acc0, acc1, acc2, acc3};
    *(float4*)&tile[ci*2+cc][w0] = o;
  }
  __syncthreads();
  const size_t obase = ((size_t)b*HW + (size_t)h*Wl)*Cc + cg*16;
#pragma unroll
  for(int i=0;i<8;i++){
    int idx = i*256 + threadIdx.x;
    int c2 = idx & 15, w2 = idx >> 4;
    xt[obase + (size_t)w2*Cc + c2] = tile[c2][w2];
  }
}

// ---------------- LayerNorm over C=128, one wave per token ----------------
__global__ __launch_bounds__(256) void ln_kernel(const float* __restrict__ xt,
                                                 const float* __restrict__ wv,
                                                 const float* __restrict__ bv,
                                                 bf16* __restrict__ xn){
  int tok  = blockIdx.x*4 + (threadIdx.x>>6);
  int lane = threadIdx.x & 63;
  const float* row = xt + (size_t)tok*Cc;
  float v0 = row[lane], v1 = row[lane+64];
  float s = v0+v1;
#pragma unroll
  for(int off=32; off; off>>=1) s += __shfl_down(s, off, 64);
  s = __shfl(s, 0, 64);
  float m = s * (1.0f/128.0f);
  float d0 = v0-m, d1 = v1-m;
  float vs = d0*d0 + d1*d1;
#pragma unroll
  for(int off=32; off; off>>=1) vs += __shfl_down(vs, off, 64);
  vs = __shfl(vs, 0, 64);
  float rstd = rsqrtf(vs*(1.0f/128.0f) + 1e-5f);
  bf16* orow = xn + (size_t)tok*Cc;
  orow[lane]    = f2b(d0*rstd*wv[lane]    + bv[lane]);
  orow[lane+64] = f2b(d1*rstd*wv[lane+64] + bv[lane+64]);
}

// ---------------- MFMA bf16 GEMM ----------------
template<int EPI>
__global__ __launch_bounds__(256) void mfma_gemm(const bf16* __restrict__ A,
                                                 const bf16* __restrict__ Wt,
                                                 const float* __restrict__ bias,
                                                 bf16* __restrict__ outb,
                                                 float* __restrict__ xt,
                                                 const float* __restrict__ ls,
                                                 int N, int K){
  __shared__ short As[128*32];
  __shared__ short Bs[64*32];
  const int m0 = blockIdx.y*128, n0 = blockIdx.x*64;
  const int tid = threadIdx.x;
  const int lane = tid & 63;
  const int w = tid >> 6;

  floatx4 acc[4][2];
#pragma unroll
  for(int i=0;i<4;i++)
#pragma unroll
    for(int j=0;j<2;j++) acc[i][j] = (floatx4){0.f,0.f,0.f,0.f};

  for(int k0=0; k0<K; k0+=32){
#pragma unroll
    for(int p=0;p<2;p++){
      int ch = tid + p*256;
      int r = ch & 127, c = ch >> 7;
      short8 v = *(const short8*)(A + (size_t)(m0+r)*K + k0 + c*8);
      int lidx = ((r>>4)*4 + c)*16 + (r&15);
      *(short8*)&As[lidx*8] = v;
    }
    {
      int n = tid & 63, c = tid >> 6;
      short8 v = *(const short8*)(Wt + (size_t)(n0+n)*K + k0 + c*8);
      int lidx = ((n>>4)*4 + c)*16 + (n&15);
      *(short8*)&Bs[lidx*8] = v;
    }
    __syncthreads();
    short8 af[4], bfr[2];
#pragma unroll
    for(int mt=0;mt<4;mt++) af[mt] = *(short8*)&As[(((w&1)*4+mt)*64 + lane)*8];
#pragma unroll
    for(int nt=0;nt<2;nt++) bfr[nt] = *(short8*)&Bs[(((w>>1)*2+nt)*64 + lane)*8];
#pragma unroll
    for(int mt=0;mt<4;mt++)
#pragma unroll
      for(int nt=0;nt<2;nt++)
        acc[mt][nt] = __builtin_amdgcn_mfma_f32_16x16x32_bf16(af[mt], bfr[nt], acc[mt][nt], 0, 0, 0);
    __syncthreads();
  }

#pragma unroll
  for(int mt=0;mt<4;mt++){
#pragma unroll
    for(int nt=0;nt<2;nt++){
#pragma unroll
      for(int r=0;r<4;r++){
        int row = m0 + (w&1)*64 + mt*16 + ((lane>>4))*4 + r;
        int col = n0 + (w>>1)*32 + nt*16 + (lane&15);
        float v = acc[mt][nt][r];
        if(EPI==0){
          outb[(size_t)row*N + col] = f2b(v);
        } else if(EPI==1){
          v += bias[col];
          v = 0.5f*v*(1.0f + erff(v*0.70710678118f));
          outb[(size_t)row*N + col] = f2b(v);
        } else if(EPI==2){
          v += bias[col];
          xt[(size_t)row*128 + col] += ls[col]*v;
        } else {
          v += bias[col];
          float rr = xt[(size_t)row*128 + col] + ls[col]*v;
          outb[(size_t)row*128 + col] = f2b(rr);
        }
      }
    }
  }
}

// ---------------- merged MFMA flash attention, one (instance, head) per block ----------------
// local: inst = ((b*16+bh)*16+bw)*4 + head          (8192 blocks, L=64)
// grid : inst = ((b*8+si)*8+sj)*4 + hl, head=4+hl   (2048 blocks, L=256)
// 4 waves: share V^T LDS buffer; each wave owns a P buffer and L/64 Q-tiles.
#define PSG 268                       // 256+12 padded stride (max case)
template<int L, int GRID>
__device__ __forceinline__ void attn_body(int inst, const bf16* __restrict__ qkv,
                                          bf16* __restrict__ a, short* smem){
  constexpr int NTILE = L/16;
  constexpr int NKB   = L/32;
  constexpr int NQW   = NTILE/4;      // Q-tiles per wave
  constexpr int PS    = L + 12;
  const int tid = threadIdx.x;
  const int w = tid >> 6, lane = tid & 63;
  const int n16 = lane & 15, quad = lane >> 4;
  short* vbuf = smem;                       // [16][PS] shared V^T
  short* pbuf = smem + 16*PS*(1 + w);       // per-wave P

  int head = inst & 3, b, r0, c0;
  if(GRID){ c0 = (inst>>2)&7;  r0 = (inst>>5)&7;  b = inst>>8;  head += 4; }
  else    { c0 = (inst>>2)&15; r0 = (inst>>6)&15; b = inst>>10; }
  const int qoff = head*16, koff = 128 + head*16, voff = 256 + head*16, ooff = head*16;

  auto tokof = [&](int g)->size_t{
    int hh, ww;
    if(GRID){ hh = (g>>4)*8 + r0; ww = (g&15)*8 + c0; }
    else    { hh = r0*8 + (g>>3); ww = c0*8 + (g&7); }
    return (size_t)b*HW + (size_t)hh*Wl + ww;
  };

  // K fragments (registers, quads 2,3 zero-padded for hd=16 in K=32)
  short8 kf[NTILE];
#pragma unroll
  for(int kt=0; kt<NTILE; kt++){
    short8 v = {0,0,0,0,0,0,0,0};
    if(quad < 2) v = *(const short8*)(qkv + tokof(kt*16 + n16)*384 + koff + quad*8);
    kf[kt] = v;
  }

  // cooperative V transpose into shared vbuf: chunk = token*2 + half
#pragma unroll
  for(int it=0; it < (2*L+255)/256; it++){
    int chunk = it*256 + tid;
    if(chunk < 2*L){
      int t = chunk >> 1, u = chunk & 1;
      short8 v = *(const short8*)(qkv + tokof(t)*384 + voff + u*8);
#pragma unroll
      for(int i=0;i<8;i++) vbuf[(u*8+i)*PS + t] = ((short*)&v)[i];
    }
  }
  __syncthreads();
  short8 vf[NKB];
#pragma unroll
  for(int kb=0; kb<NKB; kb++)
    vf[kb] = *(short8*)&vbuf[n16*PS + kb*32 + quad*8];

#pragma unroll
  for(int qi=0; qi<NQW; qi++){
    int qt = w*NQW + qi;
    short8 qf = {0,0,0,0,0,0,0,0};
    if(quad < 2) qf = *(const short8*)(qkv + tokof(qt*16 + n16)*384 + qoff + quad*8);

    floatx4 sf[NTILE];
#pragma unroll
    for(int kt=0; kt<NTILE; kt++){
      floatx4 z = (floatx4){0.f,0.f,0.f,0.f};
      sf[kt] = __builtin_amdgcn_mfma_f32_16x16x32_bf16(qf, kf[kt], z, 0, 0, 0);
    }

    float mx[4] = {-1e30f,-1e30f,-1e30f,-1e30f};
#pragma unroll
    for(int kt=0; kt<NTILE; kt++)
#pragma unroll
      for(int r=0;r<4;r++) mx[r] = fmaxf(mx[r], sf[kt][r]);
#pragma unroll
    for(int r=0;r<4;r++){
      mx[r] = fmaxf(mx[r], __shfl_xor(mx[r], 1, 64));
      mx[r] = fmaxf(mx[r], __shfl_xor(mx[r], 2, 64));
      mx[r] = fmaxf(mx[r], __shfl_xor(mx[r], 4, 64));
      mx[r] = fmaxf(mx[r], __shfl_xor(mx[r], 8, 64));
      mx[r] = -mx[r]*0.25f;           // folded into exp fma
    }

    float l[4] = {0.f,0.f,0.f,0.f};
#pragma unroll
    for(int kt=0; kt<NTILE; kt++){
#pragma unroll
      for(int r=0;r<4;r++){
        float p = __expf(__fmaf_rn(sf[kt][r], 0.25f, mx[r]));
        l[r] += p;
        bf16 pb = f2b(p);
        pbuf[(quad*4+r)*PS + kt*16 + n16] = *(short*)&pb;   // conflict-free (quad rows hit disjoint bank octets)
      }
    }
#pragma unroll
    for(int r=0;r<4;r++){
      l[r] += __shfl_xor(l[r], 1, 64);
      l[r] += __shfl_xor(l[r], 2, 64);
      l[r] += __shfl_xor(l[r], 4, 64);
      l[r] += __shfl_xor(l[r], 8, 64);
    }

    floatx4 of = (floatx4){0.f,0.f,0.f,0.f};
#pragma unroll
    for(int kb=0; kb<NKB; kb++){
      short8 pf = *(short8*)&pbuf[n16*PS + kb*32 + quad*8];
      of = __builtin_amdgcn_mfma_f32_16x16x32_bf16(pf, vf[kb], of, 0, 0, 0);
    }

#pragma unroll
    for(int r=0;r<4;r++){
      float inv = 1.0f / l[r];
      size_t t = tokof(qt*16 + quad*4 + r);
      a[t*Cc + ooff + n16] = f2b(of[r] * inv);
    }
  }
}

__global__ __launch_bounds__(256, 2) void attn_all(const bf16* __restrict__ qkv,
                                                   bf16* __restrict__ a){
  __shared__ short smem[16*PSG*5];    // 42880 B: shared V^T + 4 per-wave P buffers
  int blk = blockIdx.x;
  if(blk < 8192) attn_body<64,0>(blk, qkv, a, smem);
  else           attn_body<256,1>(blk - 8192, qkv, a, smem);
}

// ---------------- (B, HW, C) -> (B, C, HW) transpose, bf16 -> fp32 out ----------------
__global__ __launch_bounds__(256) void transpose_kernel(const bf16* __restrict__ xf,
                                                        float* __restrict__ out){
  __shared__ bf16 tile[32][33];
  int t0 = blockIdx.x*32, c0 = blockIdx.y*32, b = blockIdx.z;
  int x = threadIdx.x, y = threadIdx.y;   // 32, 8
  const bf16* src = xf + (size_t)b*HW*Cc;
  float* dst = out + (size_t)b*Cc*HW;
#pragma unroll
  for(int i=0;i<4;i++)
    tile[y*4+i][x] = src[(size_t)(t0 + y*4+i)*Cc + c0 + x];
  __syncthreads();
#pragma unroll
  for(int i=0;i<4;i++)
    dst[(size_t)(c0 + y*4+i)*HW + t0 + x] = b2f(tile[x][y*4+i]);
}

extern "C" void kernel_launch(void* const* d_in, const int* in_sizes, int n_in,
                              void* d_out, int out_size, void* d_ws, size_t ws_size,
                              hipStream_t stream) {
  const float* x       = (const float*)d_in[0];
  const float* conv_w  = (const float*)d_in[1];
  const float* conv_b  = (const float*)d_in[2];
  const float* norm1_w = (const float*)d_in[3];
  const float* norm1_b = (const float*)d_in[4];
  const float* wqkv    = (const float*)d_in[5];
  const float* proj_w  = (const float*)d_in[6];
  const float* proj_b  = (const float*)d_in[7];
  const float* norm2_w = (const float*)d_in[8];
  const float* norm2_b = (const float*)d_in[9];
  const float* fc1_w   = (const float*)d_in[10];
  const float* fc1_b   = (const float*)d_in[11];
  const float* fc2_w   = (const float*)d_in[12];
  const float* fc2_b   = (const float*)d_in[13];
  const float* ls1     = (const float*)d_in[14];
  const float* ls2     = (const float*)d_in[15];
  float* out = (float*)d_out;

  char* ws = (char*)d_ws;
  float* xt = (float*)ws;                                        // 64 MiB fp32 residual
  bf16*  sh = (bf16*)(ws + (size_t)NT*Cc*4);                     // 32 MiB: xn -> a -> xn2 -> xt_final
  bf16*  qh = (bf16*)(ws + (size_t)NT*Cc*4 + (size_t)NT*Cc*2);   // 128 MiB: qkv then h1
  bf16*  wt = (bf16*)(ws + (size_t)NT*Cc*4 + (size_t)NT*Cc*2 + (size_t)NT*512*2);
  bf16* qkvT = wt;            // 384 x 128
  bf16* projT= wt + 49152;    // 128 x 128
  bf16* fc1T = wt + 65536;    // 512 x 128
  bf16* fc2T = wt + 131072;   // 128 x 512

  transpose_all<<<196608/256, 256, 0, stream>>>(wqkv, proj_w, fc1_w, fc2_w,
                                                qkvT, projT, fc1T, fc2T);
  conv_kernel<<<Bn*8*Hh, 256, 0, stream>>>(x, conv_w, conv_b, xt);
  ln_kernel<<<NT/4, 256, 0, stream>>>(xt, norm1_w, norm1_b, sh);
  mfma_gemm<0><<<dim3(384/64, NT/128), 256, 0, stream>>>(sh, qkvT, nullptr, qh, nullptr, nullptr, 384, 128);
  attn_all<<<8192 + 2048, 256, 0, stream>>>(qh, sh);
  mfma_gemm<2><<<dim3(128/64, NT/128), 256, 0, stream>>>(sh, projT, proj_b, nullptr, xt, ls1, 128, 128);
  ln_kernel<<<NT/4, 256, 0, stream>>>(xt, norm2_w, norm2_b, sh);
  mfma_gemm<1><<<dim3(512/64, NT/128), 256, 0, stream>>>(sh, fc1T, fc1_b, qh, nullptr, nullptr, 512, 128);
  mfma_gemm<3><<<dim3(128/64, NT/128), 256, 0, stream>>>(qh, fc2T, fc2_b, sh, xt, ls2, 128, 512);
  transpose_kernel<<<dim3(HW/32, Cc/32, Bn), dim3(32,8), 0, stream>>>(sh, out);
}

// Round 7
// 567.967 us; speedup vs baseline: 2.7609x; 1.0471x over previous
//
#include <hip/hip_runtime.h>
#include <hip/hip_bf16.h>

typedef __hip_bfloat16 bf16;
typedef __attribute__((ext_vector_type(8))) short short8;
typedef __attribute__((ext_vector_type(4))) float floatx4;

#define Bn 8
#define Cc 128
#define Hh 128
#define Wl 128
#define HW (Hh*Wl)
#define NT (Bn*HW)   // 131072 tokens
#define REG 8388608  // elements per qkv phase-buffer (16 MiB bf16)

__device__ __forceinline__ float b2f(bf16 v){ return __bfloat162float(v); }
__device__ __forceinline__ bf16  f2b(float v){ return __float2bfloat16(v); }

// ---------------- all weight transposes in one launch ----------------
__global__ __launch_bounds__(256) void transpose_all(const float* __restrict__ wqkv,
                                                     const float* __restrict__ proj_w,
                                                     const float* __restrict__ fc1_w,
                                                     const float* __restrict__ fc2_w,
                                                     bf16* __restrict__ qkvT,
                                                     bf16* __restrict__ projT,
                                                     bf16* __restrict__ fc1T,
                                                     bf16* __restrict__ fc2T){
  int idx = blockIdx.x*256 + threadIdx.x;
  const float* src; bf16* dst; int K, N;
  if(idx < 49152){ src=wqkv; dst=qkvT; K=128; N=384; }
  else if(idx < 65536){ idx -= 49152; src=proj_w; dst=projT; K=128; N=128; }
  else if(idx < 131072){ idx -= 65536; src=fc1_w; dst=fc1T; K=128; N=512; }
  else { idx -= 131072; src=fc2_w; dst=fc2T; K=512; N=128; }
  int n = idx % N, k = idx / N;
  dst[(size_t)n*K + k] = f2b(src[idx]);
}

// ---------------- depthwise 3x3 conv + bias + residual -> channel-last fp32 ----------------
__global__ __launch_bounds__(256) void conv_kernel(const float* __restrict__ x,
                                                   const float* __restrict__ cw,
                                                   const float* __restrict__ cb,
                                                   float* __restrict__ xt){
  __shared__ float tile[16][132];
  int blk = blockIdx.x;              // ((b*8 + cg)*128 + h)
  int h = blk & 127; int t = blk >> 7;
  int cg = t & 7;    int b = t >> 3;
  int w4 = threadIdx.x & 31;
  int ci = threadIdx.x >> 5;
  int w0 = w4*4;
#pragma unroll
  for(int cc=0; cc<2; cc++){
    int c = cg*16 + ci*2 + cc;
    const float* xp = x + ((size_t)(b*Cc + c))*HW;
    float wg[9];
#pragma unroll
    for(int i=0;i<9;i++) wg[i] = cw[c*9+i];
    float4 rowv[3]; float lf[3], rt[3];
#pragma unroll
    for(int r=0;r<3;r++){
      int hh = h-1+r;
      float4 v = {0.f,0.f,0.f,0.f};
      if(hh>=0 && hh<Hh) v = *(const float4*)(xp + hh*Wl + w0);
      rowv[r] = v;
      float l = __shfl_up(v.w, 1, 32);
      float rr = __shfl_down(v.x, 1, 32);
      lf[r] = (w4==0)  ? 0.f : l;
      rt[r] = (w4==31) ? 0.f : rr;
    }
    float acc0 = cb[c], acc1 = cb[c], acc2 = cb[c], acc3 = cb[c];
#pragma unroll
    for(int r=0;r<3;r++){
      float4 v = rowv[r];
      acc0 += wg[r*3+0]*lf[r] + wg[r*3+1]*v.x + wg[r*3+2]*v.y;
      acc1 += wg[r*3+0]*v.x   + wg[r*3+1]*v.y + wg[r*3+2]*v.z;
      acc2 += wg[r*3+0]*v.y   + wg[r*3+1]*v.z + wg[r*3+2]*v.w;
      acc3 += wg[r*3+0]*v.z   + wg[r*3+1]*v.w + wg[r*3+2]*rt[r];
    }
    acc0 += rowv[1].x; acc1 += rowv[1].y; acc2 += rowv[1].z; acc3 += rowv[1].w;
    float4 o = {acc0, acc1, acc2, acc3};
    *(float4*)&tile[ci*2+cc][w0] = o;
  }
  __syncthreads();
  const size_t obase = ((size_t)b*HW + (size_t)h*Wl)*Cc + cg*16;
#pragma unroll
  for(int i=0;i<8;i++){
    int idx = i*256 + threadIdx.x;
    int c2 = idx & 15, w2 = idx >> 4;
    xt[obase + (size_t)w2*Cc + c2] = tile[c2][w2];
  }
}

// ---------------- LayerNorm over C=128, one wave per token ----------------
__global__ __launch_bounds__(256) void ln_kernel(const float* __restrict__ xt,
                                                 const float* __restrict__ wv,
                                                 const float* __restrict__ bv,
                                                 bf16* __restrict__ xn){
  int tok  = blockIdx.x*4 + (threadIdx.x>>6);
  int lane = threadIdx.x & 63;
  const float* row = xt + (size_t)tok*Cc;
  float v0 = row[lane], v1 = row[lane+64];
  float s = v0+v1;
#pragma unroll
  for(int off=32; off; off>>=1) s += __shfl_down(s, off, 64);
  s = __shfl(s, 0, 64);
  float m = s * (1.0f/128.0f);
  float d0 = v0-m, d1 = v1-m;
  float vs = d0*d0 + d1*d1;
#pragma unroll
  for(int off=32; off; off>>=1) vs += __shfl_down(vs, off, 64);
  vs = __shfl(vs, 0, 64);
  float rstd = rsqrtf(vs*(1.0f/128.0f) + 1e-5f);
  bf16* orow = xn + (size_t)tok*Cc;
  orow[lane]    = f2b(d0*rstd*wv[lane]    + bv[lane]);
  orow[lane+64] = f2b(d1*rstd*wv[lane+64] + bv[lane+64]);
}

// ---------------- MFMA bf16 GEMM ----------------
// EPI 0: qkv -> scatter into 6 head-major attention buffers (outb = base of qL..vG)
// EPI 1: +bias, GELU, bf16; EPI 2: +bias, xt += ls*v; EPI 3: +bias, bf16(xt + ls*v)
template<int EPI>
__global__ __launch_bounds__(256) void mfma_gemm(const bf16* __restrict__ A,
                                                 const bf16* __restrict__ Wt,
                                                 const float* __restrict__ bias,
                                                 bf16* __restrict__ outb,
                                                 float* __restrict__ xt,
                                                 const float* __restrict__ ls,
                                                 int N, int K){
  __shared__ short As[128*32];
  __shared__ short Bs[64*32];
  const int m0 = blockIdx.y*128, n0 = blockIdx.x*64;
  const int tid = threadIdx.x;
  const int lane = tid & 63;
  const int w = tid >> 6;

  floatx4 acc[4][2];
#pragma unroll
  for(int i=0;i<4;i++)
#pragma unroll
    for(int j=0;j<2;j++) acc[i][j] = (floatx4){0.f,0.f,0.f,0.f};

  for(int k0=0; k0<K; k0+=32){
#pragma unroll
    for(int p=0;p<2;p++){
      int ch = tid + p*256;
      int r = ch & 127, c = ch >> 7;
      short8 v = *(const short8*)(A + (size_t)(m0+r)*K + k0 + c*8);
      int lidx = ((r>>4)*4 + c)*16 + (r&15);
      *(short8*)&As[lidx*8] = v;
    }
    {
      int n = tid & 63, c = tid >> 6;
      short8 v = *(const short8*)(Wt + (size_t)(n0+n)*K + k0 + c*8);
      int lidx = ((n>>4)*4 + c)*16 + (n&15);
      *(short8*)&Bs[lidx*8] = v;
    }
    __syncthreads();
    short8 af[4], bfr[2];
#pragma unroll
    for(int mt=0;mt<4;mt++) af[mt] = *(short8*)&As[(((w&1)*4+mt)*64 + lane)*8];
#pragma unroll
    for(int nt=0;nt<2;nt++) bfr[nt] = *(short8*)&Bs[(((w>>1)*2+nt)*64 + lane)*8];
#pragma unroll
    for(int mt=0;mt<4;mt++)
#pragma unroll
      for(int nt=0;nt<2;nt++)
        acc[mt][nt] = __builtin_amdgcn_mfma_f32_16x16x32_bf16(af[mt], bfr[nt], acc[mt][nt], 0, 0, 0);
    __syncthreads();
  }

#pragma unroll
  for(int mt=0;mt<4;mt++){
#pragma unroll
    for(int nt=0;nt<2;nt++){
#pragma unroll
      for(int r=0;r<4;r++){
        int row = m0 + (w&1)*64 + mt*16 + ((lane>>4))*4 + r;
        int col = n0 + (w>>1)*32 + nt*16 + (lane&15);
        float v = acc[mt][nt][r];
        if(EPI==0){
          // scatter to attention layout: reg 0..5 = qL,qG,kL,kG,vL,vG
          int reg = col >> 6;
          int head = (col >> 4) & 3;
          int ch = col & 15;
          int b = row >> 14, h = (row >> 7) & 127, ww = row & 127;
          size_t didx;
          if(!(reg & 1)){
            int inst = ((b*16 + (h>>3))*16 + (ww>>3))*4 + head;
            int pos = (h&7)*8 + (ww&7);
            didx = ((size_t)inst*64 + pos)*16 + ch;
          } else {
            int inst = ((b*8 + (h&7))*8 + (ww&7))*4 + head;
            int pos = (h>>3)*16 + (ww>>3);
            didx = ((size_t)inst*256 + pos)*16 + ch;
          }
          outb[(size_t)reg*REG + didx] = f2b(v);
        } else if(EPI==1){
          v += bias[col];
          v = 0.5f*v*(1.0f + erff(v*0.70710678118f));
          outb[(size_t)row*N + col] = f2b(v);
        } else if(EPI==2){
          v += bias[col];
          xt[(size_t)row*128 + col] += ls[col]*v;
        } else {
          v += bias[col];
          float rr = xt[(size_t)row*128 + col] + ls[col]*v;
          outb[(size_t)row*128 + col] = f2b(rr);
        }
      }
    }
  }
}

// ---------------- local attention: blk = winid*4 + head, L=64 ----------------
// Dense layout: Q/K/V[blk][64 tok][16 ch]. Q/K frags: direct coalesced global loads.
__global__ __launch_bounds__(256) void attn_local2(const bf16* __restrict__ qL,
                                                   const bf16* __restrict__ kL,
                                                   const bf16* __restrict__ vL,
                                                   bf16* __restrict__ a){
  __shared__ short vt[16*72];      // V^T [16 ch][64 tok + 8 pad]
  __shared__ short pb[4][16*72];   // per-wave P
  const int tid = threadIdx.x;
  const int w = tid >> 6, lane = tid & 63;
  const int n16 = lane & 15, quad = lane >> 4;
  const int blk = blockIdx.x;
  const int head = blk & 3, winid = blk >> 2;
  const bf16* Qb = qL + (size_t)blk*1024;
  const bf16* Kb = kL + (size_t)blk*1024;
  const bf16* Vb = vL + (size_t)blk*1024;

  if(tid < 128){
    int tok = tid >> 1, u = tid & 1;
    short8 v = *(const short8*)(Vb + tok*16 + u*8);
#pragma unroll
    for(int i=0;i<8;i++) vt[(u*8+i)*72 + tok] = ((short*)&v)[i];
  }
  __syncthreads();

  const int qt = w;
  short8 qf = {0,0,0,0,0,0,0,0};
  if(quad < 2) qf = *(const short8*)(Qb + (qt*16+n16)*16 + quad*8);

  floatx4 sf[4];
#pragma unroll
  for(int kt=0; kt<4; kt++){
    short8 kf = {0,0,0,0,0,0,0,0};
    if(quad < 2) kf = *(const short8*)(Kb + (kt*16+n16)*16 + quad*8);
    floatx4 z = (floatx4){0.f,0.f,0.f,0.f};
    sf[kt] = __builtin_amdgcn_mfma_f32_16x16x32_bf16(qf, kf, z, 0, 0, 0);
  }

  float mx[4] = {-1e30f,-1e30f,-1e30f,-1e30f};
#pragma unroll
  for(int kt=0; kt<4; kt++)
#pragma unroll
    for(int r=0;r<4;r++) mx[r] = fmaxf(mx[r], sf[kt][r]);
#pragma unroll
  for(int r=0;r<4;r++){
    mx[r] = fmaxf(mx[r], __shfl_xor(mx[r], 1, 64));
    mx[r] = fmaxf(mx[r], __shfl_xor(mx[r], 2, 64));
    mx[r] = fmaxf(mx[r], __shfl_xor(mx[r], 4, 64));
    mx[r] = fmaxf(mx[r], __shfl_xor(mx[r], 8, 64));
    mx[r] = -mx[r]*0.25f;
  }
  float l[4] = {0.f,0.f,0.f,0.f};
#pragma unroll
  for(int kt=0; kt<4; kt++){
#pragma unroll
    for(int r=0;r<4;r++){
      float p = __expf(__fmaf_rn(sf[kt][r], 0.25f, mx[r]));
      l[r] += p;
      bf16 pbv = f2b(p);
      pb[w][(quad*4+r)*72 + kt*16 + n16] = *(short*)&pbv;
    }
  }
#pragma unroll
  for(int r=0;r<4;r++){
    l[r] += __shfl_xor(l[r], 1, 64);
    l[r] += __shfl_xor(l[r], 2, 64);
    l[r] += __shfl_xor(l[r], 4, 64);
    l[r] += __shfl_xor(l[r], 8, 64);
  }

  floatx4 of = (floatx4){0.f,0.f,0.f,0.f};
#pragma unroll
  for(int kb=0; kb<2; kb++){
    short8 pf = *(short8*)&pb[w][n16*72 + kb*32 + quad*8];
    short8 vfb = *(short8*)&vt[n16*72 + kb*32 + quad*8];
    of = __builtin_amdgcn_mfma_f32_16x16x32_bf16(pf, vfb, of, 0, 0, 0);
  }

  const int wj = winid & 15, wi = (winid >> 4) & 15, b = winid >> 8;
  const int ooff = head*16;
#pragma unroll
  for(int r=0;r<4;r++){
    int pos = qt*16 + quad*4 + r;
    int h = wi*8 + (pos>>3), ww = wj*8 + (pos&7);
    size_t t = (size_t)b*HW + (size_t)h*Wl + ww;
    a[t*Cc + ooff + n16] = f2b(of[r] / l[r]);
  }
}

// ---------------- grid attention: blk = ginst*4 + head, L=256 ----------------
__global__ __launch_bounds__(256) void attn_grid2(const bf16* __restrict__ qG,
                                                  const bf16* __restrict__ kG,
                                                  const bf16* __restrict__ vG,
                                                  bf16* __restrict__ a){
  __shared__ short vt[16*264];      // V^T [16 ch][256 tok + 8 pad]
  __shared__ short pb[4][16*264];   // per-wave P
  const int tid = threadIdx.x;
  const int w = tid >> 6, lane = tid & 63;
  const int n16 = lane & 15, quad = lane >> 4;
  const int blk = blockIdx.x;
  const int head = blk & 3, ginst = blk >> 2;
  const bf16* Qb = qG + (size_t)blk*4096;
  const bf16* Kb = kG + (size_t)blk*4096;
  const bf16* Vb = vG + (size_t)blk*4096;

#pragma unroll
  for(int it=0; it<2; it++){
    int chunk = it*256 + tid;
    int tok = chunk >> 1, u = chunk & 1;
    short8 v = *(const short8*)(Vb + tok*16 + u*8);
#pragma unroll
    for(int i=0;i<8;i++) vt[(u*8+i)*264 + tok] = ((short*)&v)[i];
  }
  __syncthreads();

  const int sj = ginst & 7, si = (ginst >> 3) & 7, b = ginst >> 6;
  const int ooff = 64 + head*16;

#pragma unroll
  for(int qi=0; qi<4; qi++){
    int qt = w*4 + qi;
    short8 qf = {0,0,0,0,0,0,0,0};
    if(quad < 2) qf = *(const short8*)(Qb + (qt*16+n16)*16 + quad*8);

    floatx4 sf[16];
#pragma unroll
    for(int kt=0; kt<16; kt++){
      short8 kf = {0,0,0,0,0,0,0,0};
      if(quad < 2) kf = *(const short8*)(Kb + (kt*16+n16)*16 + quad*8);
      floatx4 z = (floatx4){0.f,0.f,0.f,0.f};
      sf[kt] = __builtin_amdgcn_mfma_f32_16x16x32_bf16(qf, kf, z, 0, 0, 0);
    }

    float mx[4] = {-1e30f,-1e30f,-1e30f,-1e30f};
#pragma unroll
    for(int kt=0; kt<16; kt++)
#pragma unroll
      for(int r=0;r<4;r++) mx[r] = fmaxf(mx[r], sf[kt][r]);
#pragma unroll
    for(int r=0;r<4;r++){
      mx[r] = fmaxf(mx[r], __shfl_xor(mx[r], 1, 64));
      mx[r] = fmaxf(mx[r], __shfl_xor(mx[r], 2, 64));
      mx[r] = fmaxf(mx[r], __shfl_xor(mx[r], 4, 64));
      mx[r] = fmaxf(mx[r], __shfl_xor(mx[r], 8, 64));
      mx[r] = -mx[r]*0.25f;
    }
    float l[4] = {0.f,0.f,0.f,0.f};
#pragma unroll
    for(int kt=0; kt<16; kt++){
#pragma unroll
      for(int r=0;r<4;r++){
        float p = __expf(__fmaf_rn(sf[kt][r], 0.25f, mx[r]));
        l[r] += p;
        bf16 pbv = f2b(p);
        pb[w][(quad*4+r)*264 + kt*16 + n16] = *(short*)&pbv;
      }
    }
#pragma unroll
    for(int r=0;r<4;r++){
      l[r] += __shfl_xor(l[r], 1, 64);
      l[r] += __shfl_xor(l[r], 2, 64);
      l[r] += __shfl_xor(l[r], 4, 64);
      l[r] += __shfl_xor(l[r], 8, 64);
    }

    floatx4 of = (floatx4){0.f,0.f,0.f,0.f};
#pragma unroll
    for(int kb=0; kb<8; kb++){
      short8 pf = *(short8*)&pb[w][n16*264 + kb*32 + quad*8];
      short8 vfb = *(short8*)&vt[n16*264 + kb*32 + quad*8];
      of = __builtin_amdgcn_mfma_f32_16x16x32_bf16(pf, vfb, of, 0, 0, 0);
    }

#pragma unroll
    for(int r=0;r<4;r++){
      int pos = qt*16 + quad*4 + r;
      int h = (pos>>4)*8 + si, ww = (pos&15)*8 + sj;
      size_t t = (size_t)b*HW + (size_t)h*Wl + ww;
      a[t*Cc + ooff + n16] = f2b(of[r] / l[r]);
    }
  }
}

// ---------------- (B, HW, C) -> (B, C, HW) transpose, bf16 -> fp32 out ----------------
__global__ __launch_bounds__(256) void transpose_kernel(const bf16* __restrict__ xf,
                                                        float* __restrict__ out){
  __shared__ bf16 tile[32][33];
  int t0 = blockIdx.x*32, c0 = blockIdx.y*32, b = blockIdx.z;
  int x = threadIdx.x, y = threadIdx.y;   // 32, 8
  const bf16* src = xf + (size_t)b*HW*Cc;
  float* dst = out + (size_t)b*Cc*HW;
#pragma unroll
  for(int i=0;i<4;i++)
    tile[y*4+i][x] = src[(size_t)(t0 + y*4+i)*Cc + c0 + x];
  __syncthreads();
#pragma unroll
  for(int i=0;i<4;i++)
    dst[(size_t)(c0 + y*4+i)*HW + t0 + x] = b2f(tile[x][y*4+i]);
}

extern "C" void kernel_launch(void* const* d_in, const int* in_sizes, int n_in,
                              void* d_out, int out_size, void* d_ws, size_t ws_size,
                              hipStream_t stream) {
  const float* x       = (const float*)d_in[0];
  const float* conv_w  = (const float*)d_in[1];
  const float* conv_b  = (const float*)d_in[2];
  const float* norm1_w = (const float*)d_in[3];
  const float* norm1_b = (const float*)d_in[4];
  const float* wqkv    = (const float*)d_in[5];
  const float* proj_w  = (const float*)d_in[6];
  const float* proj_b  = (const float*)d_in[7];
  const float* norm2_w = (const float*)d_in[8];
  const float* norm2_b = (const float*)d_in[9];
  const float* fc1_w   = (const float*)d_in[10];
  const float* fc1_b   = (const float*)d_in[11];
  const float* fc2_w   = (const float*)d_in[12];
  const float* fc2_b   = (const float*)d_in[13];
  const float* ls1     = (const float*)d_in[14];
  const float* ls2     = (const float*)d_in[15];
  float* out = (float*)d_out;

  char* ws = (char*)d_ws;
  float* xt = (float*)ws;                                        // 64 MiB fp32 residual
  bf16*  sh = (bf16*)(ws + (size_t)NT*Cc*4);                     // 32 MiB: xn -> a -> xn2 -> xt_final
  bf16*  qh = (bf16*)(ws + (size_t)NT*Cc*4 + (size_t)NT*Cc*2);   // 128 MiB: qkv buffers, then h1
  bf16*  wt = (bf16*)(ws + (size_t)NT*Cc*4 + (size_t)NT*Cc*2 + (size_t)NT*512*2);
  bf16* qkvT = wt;            // 384 x 128
  bf16* projT= wt + 49152;    // 128 x 128
  bf16* fc1T = wt + 65536;    // 512 x 128
  bf16* fc2T = wt + 131072;   // 128 x 512

  transpose_all<<<196608/256, 256, 0, stream>>>(wqkv, proj_w, fc1_w, fc2_w,
                                                qkvT, projT, fc1T, fc2T);
  conv_kernel<<<Bn*8*Hh, 256, 0, stream>>>(x, conv_w, conv_b, xt);
  ln_kernel<<<NT/4, 256, 0, stream>>>(xt, norm1_w, norm1_b, sh);
  // qkv GEMM scatters into qL,qG,kL,kG,vL,vG (6 x 16 MiB at qh)
  mfma_gemm<0><<<dim3(384/64, NT/128), 256, 0, stream>>>(sh, qkvT, nullptr, qh, nullptr, nullptr, 384, 128);
  attn_grid2<<<2048, 256, 0, stream>>>(qh + (size_t)1*REG, qh + (size_t)3*REG, qh + (size_t)5*REG, sh);
  attn_local2<<<8192, 256, 0, stream>>>(qh + (size_t)0*REG, qh + (size_t)2*REG, qh + (size_t)4*REG, sh);
  mfma_gemm<2><<<dim3(128/64, NT/128), 256, 0, stream>>>(sh, projT, proj_b, nullptr, xt, ls1, 128, 128);
  ln_kernel<<<NT/4, 256, 0, stream>>>(xt, norm2_w, norm2_b, sh);
  mfma_gemm<1><<<dim3(512/64, NT/128), 256, 0, stream>>>(sh, fc1T, fc1_b, qh, nullptr, nullptr, 512, 128);
  mfma_gemm<3><<<dim3(128/64, NT/128), 256, 0, stream>>>(qh, fc2T, fc2_b, sh, xt, ls2, 128, 512);
  transpose_kernel<<<dim3(HW/32, Cc/32, Bn), dim3(32,8), 0, stream>>>(sh, out);
}